// Round 6
// baseline (554.899 us; speedup 1.0000x reference)
//
#include <hip/hip_runtime.h>
#include <hip/hip_bf16.h>
#include <hip/hip_fp16.h>
#include <math.h>

#define HEADS 4
#define CAP 64    // max in-degree incl. self-loop (Poisson(17) tail; clamped)
#define SBL 256   // scatter blocks (node ranges)

typedef _Float16 half8_t __attribute__((ext_vector_type(8)));
typedef float float4_t __attribute__((ext_vector_type(4)));

// -------- prep: W1^T fp16 + W2^T fp16 + graph bounds ------------------------

__global__ __launch_bounds__(256) void prep_k(const float* __restrict__ W1, _Float16* __restrict__ W1T,
                                              const float* __restrict__ W2, _Float16* __restrict__ W2T,
                                              const int* __restrict__ batch, int N,
                                              int* __restrict__ bstart) {
    int bx = blockIdx.x;
    if (bx < 128) {
        int k = bx;                // 0..127
        int n = threadIdx.x;       // 0..255
        W1T[n * 128 + k] = (_Float16)W1[k * 256 + n];
    } else if (bx < 192) {
        int n = bx - 128;          // 0..63
        int k = threadIdx.x;       // 0..255
        W2T[n * 256 + k] = (_Float16)W2[k * 64 + n];
    } else {
        int t = threadIdx.x;
        if (t <= 64) {
            int lo = 0, hi = N;
            while (lo < hi) {
                int mid = (lo + hi) >> 1;
                if (batch[mid] < t) lo = mid + 1; else hi = mid;
            }
            bstart[t] = lo;
        }
    }
}

// ---- fused: node-range broadcast-scan scatter (LDS ranks) ∥ MFMA GEMM1 -----
// Scatter: block b owns nodes [b*NR,(b+1)*NR); scans ALL dst (L2-resident
// stream), claims ranks in LDS, writes slots + cnt. Zero device atomics.

__global__ __launch_bounds__(256) void fused_scatter_gemm1_k(
    const int* __restrict__ src, const int* __restrict__ dst, int E,
    int* __restrict__ cnt, unsigned short* __restrict__ slots, int Nn,
    const float* __restrict__ A,       // [M][128] fp32 (x)
    const _Float16* __restrict__ BT,   // [256][128] (W1^T)
    __half* __restrict__ hout,         // [M][256] fp16
    const float* __restrict__ avs,     // [4][64]
    const float* __restrict__ avd,
    float* __restrict__ os,            // [M][4]
    float* __restrict__ od, int M) {
    __shared__ int lc[512];                  // rank counters for the node range (N<=131072)
    __shared__ _Float16 lds[4 * 16 * 72];    // 9 KB; GEMM1 staging

    if ((int)blockIdx.x < SBL) {
        // ---- scatter branch ----
        int b = blockIdx.x;
        int NR = (Nn + SBL - 1) / SBL;       // 196 for N=50000
        int lo = b * NR, hi = min(lo + NR, Nn);
        int nloc = hi - lo;
        int t = threadIdx.x;
        for (int j = t; j < nloc; j += 256) {
            lc[j] = 1;                                        // pos 0 = self-loop
            slots[(size_t)(lo + j) * CAP] = (unsigned short)(lo + j);
        }
        __syncthreads();

        const int4* dst4 = (const int4*)dst;
        int nq = E >> 2;
        int base = 0;
        for (; base + 1024 <= nq; base += 1024) {
            int4 v[4];
            #pragma unroll
            for (int k = 0; k < 4; k++) v[k] = dst4[base + t + k * 256];
            #pragma unroll
            for (int k = 0; k < 4; k++) {
                int i0 = (base + t + k * 256) * 4;
                int dd[4] = { v[k].x, v[k].y, v[k].z, v[k].w };
                #pragma unroll
                for (int e = 0; e < 4; e++) {
                    int d = dd[e];
                    if (d >= lo && d < hi) {
                        int s = src[i0 + e];
                        int pos = atomicAdd(&lc[d - lo], 1);
                        if (pos < CAP) slots[(size_t)d * CAP + pos] = (unsigned short)s;
                    }
                }
            }
        }
        for (int i4 = base + t; i4 < nq; i4 += 256) {
            int4 v = dst4[i4];
            int i0 = i4 * 4;
            int dd[4] = { v.x, v.y, v.z, v.w };
            #pragma unroll
            for (int e = 0; e < 4; e++) {
                int d = dd[e];
                if (d >= lo && d < hi) {
                    int s = src[i0 + e];
                    int pos = atomicAdd(&lc[d - lo], 1);
                    if (pos < CAP) slots[(size_t)d * CAP + pos] = (unsigned short)s;
                }
            }
        }
        for (int i = (nq << 2) + t; i < E; i += 256) {
            int d = dst[i];
            if (d >= lo && d < hi) {
                int s = src[i];
                int pos = atomicAdd(&lc[d - lo], 1);
                if (pos < CAP) slots[(size_t)d * CAP + pos] = (unsigned short)s;
            }
        }
        __syncthreads();
        for (int j = t; j < nloc; j += 256) cnt[lo + j] = lc[j];
        return;
    }

    // ---- GEMM1 branch ----
    int bx = blockIdx.x - SBL;
    int wave = threadIdx.x >> 6;
    int lane = threadIdx.x & 63;
    int q = lane >> 4;
    int c16 = lane & 15;
    int row0 = bx * 64 + wave * 16;

    half8_t a[4];
    int ar = row0 + c16;
    bool avalid = (ar < M);
    const float* ap = A + (size_t)ar * 128;
    #pragma unroll
    for (int ks = 0; ks < 4; ks++) {
        if (avalid) {
            float4 f0 = *(const float4*)(ap + ks * 32 + q * 8);
            float4 f1 = *(const float4*)(ap + ks * 32 + q * 8 + 4);
            half8_t h;
            h[0] = (_Float16)f0.x; h[1] = (_Float16)f0.y;
            h[2] = (_Float16)f0.z; h[3] = (_Float16)f0.w;
            h[4] = (_Float16)f1.x; h[5] = (_Float16)f1.y;
            h[6] = (_Float16)f1.z; h[7] = (_Float16)f1.w;
            a[ks] = h;
        } else {
            a[ks] = (half8_t)(_Float16)0.0f;
        }
    }

    float4_t acc[16];
    #pragma unroll
    for (int ct = 0; ct < 16; ct++) acc[ct] = (float4_t)0.f;

    #pragma unroll
    for (int ks = 0; ks < 4; ks++) {
        #pragma unroll
        for (int ct = 0; ct < 16; ct++) {
            half8_t b = *(const half8_t*)(BT + (size_t)(ct * 16 + c16) * 128 + ks * 32 + q * 8);
            acc[ct] = __builtin_amdgcn_mfma_f32_16x16x32_f16(a[ks], b, acc[ct], 0, 0, 0);
        }
    }

    // alpha dot partials (head h = ct>>2, chan-in-head = (ct&3)*16 + c16)
    float psh[4][4] = {}, pdh[4][4] = {};
    #pragma unroll
    for (int ct = 0; ct < 16; ct++) {
        int h = ct >> 2;
        int cih = (ct & 3) * 16 + c16;
        float as_v = avs[h * 64 + cih];
        float ad_v = avd[h * 64 + cih];
        #pragma unroll
        for (int r = 0; r < 4; r++) {
            psh[h][r] = fmaf(acc[ct][r], as_v, psh[h][r]);
            pdh[h][r] = fmaf(acc[ct][r], ad_v, pdh[h][r]);
        }
    }
    #pragma unroll
    for (int h = 0; h < 4; h++) {
        #pragma unroll
        for (int r = 0; r < 4; r++) {
            #pragma unroll
            for (int o = 8; o >= 1; o >>= 1) {
                psh[h][r] += __shfl_down(psh[h][r], o, 16);
                pdh[h][r] += __shfl_down(pdh[h][r], o, 16);
            }
        }
    }
    if (c16 == 0) {
        #pragma unroll
        for (int r = 0; r < 4; r++) {
            int gr = row0 + q * 4 + r;
            if (gr < M) {
                #pragma unroll
                for (int h = 0; h < 4; h++) {
                    os[(size_t)gr * HEADS + h] = psh[h][r];
                    od[(size_t)gr * HEADS + h] = pdh[h][r];
                }
            }
        }
    }

    // fp16 store via per-wave chunked LDS staging (stride 72 halfs = 144 B)
    _Float16* wl = lds + wave * (16 * 72);
    #pragma unroll
    for (int chunk = 0; chunk < 4; chunk++) {
        #pragma unroll
        for (int c4 = 0; c4 < 4; c4++) {
            int ct = chunk * 4 + c4;
            #pragma unroll
            for (int r = 0; r < 4; r++) {
                wl[(q * 4 + r) * 72 + c4 * 16 + c16] = (_Float16)acc[ct][r];
            }
        }
        __syncthreads();
        #pragma unroll
        for (int pass = 0; pass < 2; pass++) {
            int idx8 = pass * 64 + lane;   // 128 half8 units (16 rows x 8)
            int row = idx8 >> 3;
            int col8 = idx8 & 7;
            int gr = row0 + row;
            if (gr < M) {
                *(half8_t*)(hout + (size_t)gr * 256 + chunk * 64 + col8 * 8) =
                    *(const half8_t*)(wl + row * 72 + col8 * 8);
            }
        }
        __syncthreads();
    }
}

// ---------------- MFMA GEMM layer 2: h2 = g1 @ W2 ----------------

__global__ __launch_bounds__(256) void mfma_gemm2_k(
    const _Float16* __restrict__ Ah,   // [M][256] fp16 (g1)
    const _Float16* __restrict__ BT,   // [64][256] (W2^T)
    __half* __restrict__ hout,         // [M][64] fp16
    const float* __restrict__ avs,     // [4][16]
    const float* __restrict__ avd,
    float* __restrict__ os,            // [M][4]
    float* __restrict__ od, int M) {
    __shared__ _Float16 lds[4 * 16 * 64];
    int wave = threadIdx.x >> 6;
    int lane = threadIdx.x & 63;
    int q = lane >> 4;
    int c16 = lane & 15;
    int row0 = blockIdx.x * 64 + wave * 16;

    half8_t a[8];
    int ar = row0 + c16;
    bool avalid = (ar < M);
    const _Float16* ap = Ah + (size_t)ar * 256;
    #pragma unroll
    for (int ks = 0; ks < 8; ks++) {
        if (avalid) a[ks] = *(const half8_t*)(ap + ks * 32 + q * 8);
        else        a[ks] = (half8_t)(_Float16)0.0f;
    }

    float4_t acc[4];
    #pragma unroll
    for (int ct = 0; ct < 4; ct++) acc[ct] = (float4_t)0.f;

    #pragma unroll
    for (int ks = 0; ks < 8; ks++) {
        #pragma unroll
        for (int ct = 0; ct < 4; ct++) {
            half8_t b = *(const half8_t*)(BT + (size_t)(ct * 16 + c16) * 256 + ks * 32 + q * 8);
            acc[ct] = __builtin_amdgcn_mfma_f32_16x16x32_f16(a[ks], b, acc[ct], 0, 0, 0);
        }
    }

    float ps[4][4], pd[4][4];
    #pragma unroll
    for (int ct = 0; ct < 4; ct++) {
        float as_v = avs[ct * 16 + c16];
        float ad_v = avd[ct * 16 + c16];
        #pragma unroll
        for (int r = 0; r < 4; r++) {
            ps[ct][r] = acc[ct][r] * as_v;
            pd[ct][r] = acc[ct][r] * ad_v;
            #pragma unroll
            for (int o = 8; o >= 1; o >>= 1) {
                ps[ct][r] += __shfl_down(ps[ct][r], o, 16);
                pd[ct][r] += __shfl_down(pd[ct][r], o, 16);
            }
        }
    }
    if (c16 == 0) {
        #pragma unroll
        for (int r = 0; r < 4; r++) {
            int gr = row0 + q * 4 + r;
            if (gr < M) {
                #pragma unroll
                for (int ct = 0; ct < 4; ct++) {
                    os[(size_t)gr * HEADS + ct] = ps[ct][r];
                    od[(size_t)gr * HEADS + ct] = pd[ct][r];
                }
            }
        }
    }

    _Float16* wl = lds + wave * (16 * 64);
    #pragma unroll
    for (int ct = 0; ct < 4; ct++) {
        #pragma unroll
        for (int r = 0; r < 4; r++) {
            wl[(q * 4 + r) * 64 + ct * 16 + c16] = (_Float16)acc[ct][r];
        }
    }
    __syncthreads();
    #pragma unroll
    for (int pass = 0; pass < 2; pass++) {
        int idx8 = pass * 64 + lane;
        int row = idx8 >> 3;
        int col8 = idx8 & 7;
        int gr = row0 + row;
        if (gr < M) {
            *(half8_t*)(hout + (size_t)gr * 64 + col8 * 8) =
                *(const half8_t*)(wl + row * 64 + col8 * 8);
        }
    }
}

// ---------------- GAT aggregation layer 1 (C=64, fp16 gather, fp16 out) -----
// single-pass softmax (deg <= CAP=64), 8 gather rows in flight per wave.

__global__ __launch_bounds__(256) void gat_agg64_f16_k(
    const __half* __restrict__ hsrc,  // [N, 256] fp16
    const float* __restrict__ as,     // [N, 4]
    const float* __restrict__ ad,     // [N, 4]
    const int* __restrict__ cnt,      // [N] degree (incl self-loop)
    const unsigned short* __restrict__ slots,  // [N*CAP]
    const float* __restrict__ bias,   // [256]
    __half* __restrict__ outh,        // [N, 256] fp16 (post-ReLU g1)
    int N) {
    int node = blockIdx.x * 4 + (threadIdx.x >> 6);
    if (node >= N) return;
    int l = threadIdx.x & 63;
    int h = l >> 4;
    int je = l & 15;
    int hb = h << 4;
    int deg = min(cnt[node], CAP);
    const unsigned short* sp = slots + (size_t)node * CAP;
    float adh = ad[(size_t)node * HEADS + h];
    float4 bv = *(const float4*)(bias + l * 4);

    // ---- phase 1: all e values ----
    int sv[4];
    float ev[4];
    #pragma unroll
    for (int k = 0; k < 4; k++) {
        int j = k * 16 + je;
        sv[k] = (j < deg) ? (int)sp[j] : 0;
    }
    #pragma unroll
    for (int k = 0; k < 4; k++) {
        int j = k * 16 + je;
        if (j < deg) {
            float a = as[(size_t)sv[k] * HEADS + h] + adh;
            ev[k] = (a > 0.f) ? a : 0.2f * a;
        } else {
            ev[k] = -INFINITY;
        }
    }
    float m = fmaxf(fmaxf(ev[0], ev[1]), fmaxf(ev[2], ev[3]));
    #pragma unroll
    for (int o = 8; o >= 1; o >>= 1) m = fmaxf(m, __shfl_xor(m, o));
    float pv[4];
    float den = 0.f;
    #pragma unroll
    for (int k = 0; k < 4; k++) {
        pv[k] = (k * 16 + je < deg) ? __expf(ev[k] - m) : 0.f;
        den += pv[k];
    }
    #pragma unroll
    for (int o = 8; o >= 1; o >>= 1) den += __shfl_xor(den, o);

    // ---- phase 2: accumulate, 8 broadcasts + 8 row-loads in flight ----
    float4 acc = make_float4(0.f, 0.f, 0.f, 0.f);
    #pragma unroll
    for (int k = 0; k < 4; k++) {
        int base = k * 16;
        if (base >= deg) break;
        int cl = min(16, deg - base);
        #pragma unroll
        for (int half = 0; half < 2; half++) {
            int j0 = half * 8;
            if (j0 >= cl) break;
            float pj[8]; int sj[8];
            #pragma unroll
            for (int jj = 0; jj < 8; jj++) {
                pj[jj] = __shfl(pv[k], hb + j0 + jj);
                sj[jj] = __shfl(sv[k], hb + j0 + jj);
            }
            uint2 rv[8];
            #pragma unroll
            for (int jj = 0; jj < 8; jj++) {
                if (j0 + jj < cl) rv[jj] = *(const uint2*)(hsrc + (size_t)sj[jj] * 256 + l * 4);
            }
            #pragma unroll
            for (int jj = 0; jj < 8; jj++) {
                if (j0 + jj < cl) {
                    float2 a0 = __half22float2(*(__half2*)&rv[jj].x);
                    float2 b0 = __half22float2(*(__half2*)&rv[jj].y);
                    acc.x = fmaf(pj[jj], a0.x, acc.x); acc.y = fmaf(pj[jj], a0.y, acc.y);
                    acc.z = fmaf(pj[jj], b0.x, acc.z); acc.w = fmaf(pj[jj], b0.y, acc.w);
                }
            }
        }
    }

    float inv = 1.f / den;
    float rx = fmaxf(fmaf(acc.x, inv, bv.x), 0.f);
    float ry = fmaxf(fmaf(acc.y, inv, bv.y), 0.f);
    float rz = fmaxf(fmaf(acc.z, inv, bv.z), 0.f);
    float rw = fmaxf(fmaf(acc.w, inv, bv.w), 0.f);
    __half2* op = (__half2*)(outh + (size_t)node * 256 + l * 4);
    op[0] = __floats2half2_rn(rx, ry);
    op[1] = __floats2half2_rn(rz, rw);
}

// ---------------- GAT aggregation layer 2 (C=16, fp16 gather, MLP=4) --------

__global__ __launch_bounds__(256) void gat_agg16_f16_k(
    const __half* __restrict__ hsrc,  // [N, 64] fp16
    const float* __restrict__ as,
    const float* __restrict__ ad,
    const int* __restrict__ cnt,
    const unsigned short* __restrict__ slots,
    const float* __restrict__ bias,   // [64]
    float* __restrict__ out, int N) {
    int node = blockIdx.x * 4 + (threadIdx.x >> 6);
    if (node >= N) return;
    int l = threadIdx.x & 63;
    int ha = l >> 4;
    int je = l & 15;
    int q = l & 15;
    int hh = q >> 2;
    int eg = l >> 4;
    int deg = min(cnt[node], CAP);
    const unsigned short* sp = slots + (size_t)node * CAP;
    float adh = ad[(size_t)node * HEADS + ha];
    float m = -INFINITY, den = 0.f;
    float4 acc = make_float4(0.f, 0.f, 0.f, 0.f);
    for (int base = 0; base < deg; base += 16) {
        int cl = min(16, deg - base);
        int s = 0;
        float e = -INFINITY;
        if (je < cl) {
            s = sp[base + je];
            float a = as[(size_t)s * HEADS + ha] + adh;
            e = (a > 0.f) ? a : 0.2f * a;
        }
        float cmax = e;
        #pragma unroll
        for (int o = 8; o >= 1; o >>= 1) cmax = fmaxf(cmax, __shfl_xor(cmax, o));
        float m_new = fmaxf(m, cmax);
        float p = (je < cl) ? __expf(e - m_new) : 0.f;
        float sum = p;
        #pragma unroll
        for (int o = 8; o >= 1; o >>= 1) sum += __shfl_xor(sum, o);
        float sc = __expf(m - m_new);
        den = den * sc + sum;
        m = m_new;
        float sch = __shfl(sc, hh << 4);
        acc.x *= sch; acc.y *= sch; acc.z *= sch; acc.w *= sch;

        int jbase = eg * 4;
        float pj[4]; int sj[4]; bool vj[4];
        #pragma unroll
        for (int jj = 0; jj < 4; jj++) {
            int j = jbase + jj;
            int jc = min(j, cl - 1);
            pj[jj] = __shfl(p, (hh << 4) + jc);
            sj[jj] = __shfl(s, (hh << 4) + jc);
            vj[jj] = (j < cl);
        }
        uint2 rv[4];
        #pragma unroll
        for (int jj = 0; jj < 4; jj++) {
            if (vj[jj]) rv[jj] = *(const uint2*)(hsrc + (size_t)sj[jj] * 64 + q * 4);
        }
        #pragma unroll
        for (int jj = 0; jj < 4; jj++) {
            if (vj[jj]) {
                float2 f0 = __half22float2(*(__half2*)&rv[jj].x);
                float2 f1 = __half22float2(*(__half2*)&rv[jj].y);
                acc.x = fmaf(pj[jj], f0.x, acc.x); acc.y = fmaf(pj[jj], f0.y, acc.y);
                acc.z = fmaf(pj[jj], f1.x, acc.z); acc.w = fmaf(pj[jj], f1.y, acc.w);
            }
        }
    }
    acc.x += __shfl_xor(acc.x, 16); acc.y += __shfl_xor(acc.y, 16);
    acc.z += __shfl_xor(acc.z, 16); acc.w += __shfl_xor(acc.w, 16);
    acc.x += __shfl_xor(acc.x, 32); acc.y += __shfl_xor(acc.y, 32);
    acc.z += __shfl_xor(acc.z, 32); acc.w += __shfl_xor(acc.w, 32);
    float denh = __shfl(den, hh << 4);
    if (eg == 0) {
        float inv = 1.f / denh;
        float4 bv = *(const float4*)(bias + q * 4);
        float4 r;
        r.x = fmaxf(fmaf(acc.x, inv, bv.x), 0.f);
        r.y = fmaxf(fmaf(acc.y, inv, bv.y), 0.f);
        r.z = fmaxf(fmaf(acc.z, inv, bv.z), 0.f);
        r.w = fmaxf(fmaf(acc.w, inv, bv.w), 0.f);
        *(float4*)(out + (size_t)node * 64 + q * 4) = r;
    }
}

// ---------------- fused mean-pool + FC (one block per graph) ----------------

__global__ __launch_bounds__(256) void poolfc_k(const float* __restrict__ g2,
                                                const int* __restrict__ bstart,
                                                const float* __restrict__ w,
                                                const float* __restrict__ b,
                                                float* __restrict__ out) {
    __shared__ float red[4][64];
    __shared__ float pooled[64];
    int g = blockIdx.x;
    int lo = bstart[g], hi = bstart[g + 1];
    int c = threadIdx.x & 63;
    int r = threadIdx.x >> 6;
    float acc = 0.f;
    for (int n = lo + r; n < hi; n += 4) acc += g2[(size_t)n * 64 + c];
    red[r][c] = acc;
    __syncthreads();
    if (threadIdx.x < 64) {
        float inv = 1.f / (float)max(hi - lo, 1);
        pooled[threadIdx.x] = (red[0][threadIdx.x] + red[1][threadIdx.x] +
                               red[2][threadIdx.x] + red[3][threadIdx.x]) * inv;
    }
    __syncthreads();
    if (threadIdx.x < 32) {
        int o = threadIdx.x;
        float a = b[o];
        #pragma unroll 8
        for (int k = 0; k < 64; k++) a = fmaf(pooled[k], w[k * 32 + o], a);
        out[g * 32 + o] = a;
    }
}

// ---------------- launch ----------------

static inline size_t align_up(size_t x, size_t a) { return (x + a - 1) & ~(a - 1); }

extern "C" void kernel_launch(void* const* d_in, const int* in_sizes, int n_in,
                              void* d_out, int out_size, void* d_ws, size_t ws_size,
                              hipStream_t stream) {
    const float* x      = (const float*)d_in[0];
    const int*   ei     = (const int*)d_in[1];
    const int*   batch  = (const int*)d_in[2];
    const float* W1     = (const float*)d_in[3];
    const float* a_src1 = (const float*)d_in[4];
    const float* a_dst1 = (const float*)d_in[5];
    const float* b1     = (const float*)d_in[6];
    const float* W2     = (const float*)d_in[7];
    const float* a_src2 = (const float*)d_in[8];
    const float* a_dst2 = (const float*)d_in[9];
    const float* b2     = (const float*)d_in[10];
    const float* fc_w   = (const float*)d_in[11];
    const float* fc_b   = (const float*)d_in[12];
    float* out = (float*)d_out;

    const int N = in_sizes[2];
    const int E = in_sizes[1] / 2;
    const int F_in = in_sizes[0] / N;   // 128
    const int D1 = HEADS * 64;          // 256
    const int D2 = HEADS * 16;          // 64

    const int* src = ei;
    const int* dst = ei + E;

    char* w = (char*)d_ws;
    size_t off = 0;
    auto alloc = [&](size_t bytes) {
        size_t p = off;
        off = align_up(off + bytes, 256);
        return (void*)(w + p);
    };
    int* cnt    = (int*)alloc((size_t)N * 4);
    unsigned short* slots = (unsigned short*)alloc((size_t)N * CAP * 2);
    int* bstart = (int*)alloc(65 * 4);
    float* as1  = (float*)alloc((size_t)N * HEADS * 4);
    float* ad1  = (float*)alloc((size_t)N * HEADS * 4);
    float* as2  = (float*)alloc((size_t)N * HEADS * 4);
    float* ad2  = (float*)alloc((size_t)N * HEADS * 4);
    __half* h1h = (__half*)alloc((size_t)N * D1 * 2);
    __half* g1h = (__half*)alloc((size_t)N * D1 * 2);
    __half* h2h = (__half*)alloc((size_t)N * D2 * 2);
    float* g2   = (float*)alloc((size_t)N * D2 * 4);
    _Float16* w1t = (_Float16*)alloc((size_t)F_in * D1 * 2);  // [256][128]
    _Float16* w2t = (_Float16*)alloc((size_t)D1 * D2 * 2);    // [64][256]

    // --- prep: W1T + W2T + graph bounds ---
    prep_k<<<193, 256, 0, stream>>>(W1, w1t, W2, w2t, batch, N, bstart);

    // --- fused: node-range scatter (no device atomics) ∥ layer-1 GEMM ---
    const int GB = (N + 63) / 64;
    fused_scatter_gemm1_k<<<SBL + GB, 256, 0, stream>>>(
        src, dst, E, cnt, slots, N,
        x, w1t, h1h, a_src1, a_dst1, as1, ad1, N);

    // --- layer 1 aggregation ---
    gat_agg64_f16_k<<<(N + 3) / 4, 256, 0, stream>>>(h1h, as1, ad1, cnt, slots, b1, g1h, N);

    // --- layer 2 ---
    mfma_gemm2_k<<<(N + 63) / 64, 256, 0, stream>>>((const _Float16*)g1h, w2t, h2h,
                                                    a_src2, a_dst2, as2, ad2, N);
    gat_agg16_f16_k<<<(N + 3) / 4, 256, 0, stream>>>(h2h, as2, ad2, cnt, slots, b2, g2, N);

    // --- fused mean-pool + fc ---
    poolfc_k<<<64, 256, 0, stream>>>(g2, bstart, fc_w, fc_b, out);
}

// Round 7
// 344.569 us; speedup vs baseline: 1.6104x; 1.6104x over previous
//
#include <hip/hip_runtime.h>
#include <hip/hip_bf16.h>
#include <hip/hip_fp16.h>
#include <math.h>

#define HEADS 4
#define CAP 64   // max in-degree incl. self-loop (Poisson(17) tail; clamped)

typedef _Float16 half8_t __attribute__((ext_vector_type(8)));
typedef float float4_t __attribute__((ext_vector_type(4)));

// -------- merged prep: cnt/slots init + W1^T fp16 + W2^T fp16 + bounds ------

__global__ __launch_bounds__(256) void prep_k(int* cnt, unsigned short* slots, int N, int NB,
                                              const float* __restrict__ W1, _Float16* __restrict__ W1T,
                                              const float* __restrict__ W2, _Float16* __restrict__ W2T,
                                              const int* __restrict__ batch, int* __restrict__ bstart) {
    int bx = blockIdx.x;
    if (bx < NB) {
        int i = bx * 256 + threadIdx.x;
        if (i < N) {
            cnt[i] = 1;
            slots[(size_t)i * CAP] = (unsigned short)i;
        }
    } else if (bx < NB + 128) {
        int k = bx - NB;           // 0..127
        int n = threadIdx.x;       // 0..255
        W1T[n * 128 + k] = (_Float16)W1[k * 256 + n];
    } else if (bx < NB + 192) {
        int n = bx - NB - 128;     // 0..63
        int k = threadIdx.x;       // 0..255
        W2T[n * 256 + k] = (_Float16)W2[k * 64 + n];
    } else {
        int t = threadIdx.x;
        if (t <= 64) {
            int lo = 0, hi = N;
            while (lo < hi) {
                int mid = (lo + hi) >> 1;
                if (batch[mid] < t) lo = mid + 1; else hi = mid;
            }
            bstart[t] = lo;
        }
    }
}

// ---------------- fused: edge scatter (8-wide phased MLP) ∥ MFMA GEMM1 ------

__global__ __launch_bounds__(256) void fused_scatter_gemm1_k(
    const int* __restrict__ src, const int* __restrict__ dst,
    int* __restrict__ cnt, unsigned short* __restrict__ slots, int E, int SB,
    const float* __restrict__ A,       // [M][128] fp32 (x)
    const _Float16* __restrict__ BT,   // [256][128] (W1^T)
    __half* __restrict__ hout,         // [M][256] fp16
    const float* __restrict__ avs,     // [4][64]
    const float* __restrict__ avd,
    float* __restrict__ os,            // [M][4]
    float* __restrict__ od, int M) {
    __shared__ _Float16 lds[4 * 16 * 72];   // 9 KB; per-wave 16x64 chunk (stride 72)

    if ((int)blockIdx.x < SB) {
        // ---- scatter branch: 8 edges per thread, phased for MLP ----
        int T = SB * 256;
        int t0 = blockIdx.x * 256 + threadIdx.x;
        int d[8], s[8];
        #pragma unroll
        for (int k = 0; k < 8; k++) {
            int i = t0 + k * T;
            if (i < E) { d[k] = dst[i]; s[k] = src[i]; }
            else d[k] = -1;
        }
        int p[8];
        #pragma unroll
        for (int k = 0; k < 8; k++) {
            if (d[k] >= 0) p[k] = atomicAdd(&cnt[d[k]], 1);
        }
        #pragma unroll
        for (int k = 0; k < 8; k++) {
            if (d[k] >= 0 && p[k] < CAP)
                slots[(size_t)d[k] * CAP + p[k]] = (unsigned short)s[k];
        }
        return;
    }

    // ---- GEMM1 branch ----
    int bx = blockIdx.x - SB;
    int wave = threadIdx.x >> 6;
    int lane = threadIdx.x & 63;
    int q = lane >> 4;
    int c16 = lane & 15;
    int row0 = bx * 64 + wave * 16;

    half8_t a[4];
    int ar = row0 + c16;
    bool avalid = (ar < M);
    const float* ap = A + (size_t)ar * 128;
    #pragma unroll
    for (int ks = 0; ks < 4; ks++) {
        if (avalid) {
            float4 f0 = *(const float4*)(ap + ks * 32 + q * 8);
            float4 f1 = *(const float4*)(ap + ks * 32 + q * 8 + 4);
            half8_t h;
            h[0] = (_Float16)f0.x; h[1] = (_Float16)f0.y;
            h[2] = (_Float16)f0.z; h[3] = (_Float16)f0.w;
            h[4] = (_Float16)f1.x; h[5] = (_Float16)f1.y;
            h[6] = (_Float16)f1.z; h[7] = (_Float16)f1.w;
            a[ks] = h;
        } else {
            a[ks] = (half8_t)(_Float16)0.0f;
        }
    }

    float4_t acc[16];
    #pragma unroll
    for (int ct = 0; ct < 16; ct++) acc[ct] = (float4_t)0.f;

    #pragma unroll
    for (int ks = 0; ks < 4; ks++) {
        #pragma unroll
        for (int ct = 0; ct < 16; ct++) {
            half8_t b = *(const half8_t*)(BT + (size_t)(ct * 16 + c16) * 128 + ks * 32 + q * 8);
            acc[ct] = __builtin_amdgcn_mfma_f32_16x16x32_f16(a[ks], b, acc[ct], 0, 0, 0);
        }
    }

    // alpha dot partials (head h = ct>>2, chan-in-head = (ct&3)*16 + c16)
    float psh[4][4] = {}, pdh[4][4] = {};
    #pragma unroll
    for (int ct = 0; ct < 16; ct++) {
        int h = ct >> 2;
        int cih = (ct & 3) * 16 + c16;
        float as_v = avs[h * 64 + cih];
        float ad_v = avd[h * 64 + cih];
        #pragma unroll
        for (int r = 0; r < 4; r++) {
            psh[h][r] = fmaf(acc[ct][r], as_v, psh[h][r]);
            pdh[h][r] = fmaf(acc[ct][r], ad_v, pdh[h][r]);
        }
    }
    #pragma unroll
    for (int h = 0; h < 4; h++) {
        #pragma unroll
        for (int r = 0; r < 4; r++) {
            #pragma unroll
            for (int o = 8; o >= 1; o >>= 1) {
                psh[h][r] += __shfl_down(psh[h][r], o, 16);
                pdh[h][r] += __shfl_down(pdh[h][r], o, 16);
            }
        }
    }
    if (c16 == 0) {
        #pragma unroll
        for (int r = 0; r < 4; r++) {
            int gr = row0 + q * 4 + r;
            if (gr < M) {
                #pragma unroll
                for (int h = 0; h < 4; h++) {
                    os[(size_t)gr * HEADS + h] = psh[h][r];
                    od[(size_t)gr * HEADS + h] = pdh[h][r];
                }
            }
        }
    }

    // fp16 store via per-wave chunked LDS staging (stride 72 halfs = 144 B)
    _Float16* wl = lds + wave * (16 * 72);
    #pragma unroll
    for (int chunk = 0; chunk < 4; chunk++) {
        #pragma unroll
        for (int c4 = 0; c4 < 4; c4++) {
            int ct = chunk * 4 + c4;
            #pragma unroll
            for (int r = 0; r < 4; r++) {
                wl[(q * 4 + r) * 72 + c4 * 16 + c16] = (_Float16)acc[ct][r];
            }
        }
        __syncthreads();
        #pragma unroll
        for (int pass = 0; pass < 2; pass++) {
            int idx8 = pass * 64 + lane;   // 128 half8 units (16 rows x 8)
            int row = idx8 >> 3;
            int col8 = idx8 & 7;
            int gr = row0 + row;
            if (gr < M) {
                *(half8_t*)(hout + (size_t)gr * 256 + chunk * 64 + col8 * 8) =
                    *(const half8_t*)(wl + row * 72 + col8 * 8);
            }
        }
        __syncthreads();
    }
}

// ---------------- MFMA GEMM layer 2: h2 = g1 @ W2 ----------------

__global__ __launch_bounds__(256) void mfma_gemm2_k(
    const _Float16* __restrict__ Ah,   // [M][256] fp16 (g1)
    const _Float16* __restrict__ BT,   // [64][256] (W2^T)
    __half* __restrict__ hout,         // [M][64] fp16
    const float* __restrict__ avs,     // [4][16]
    const float* __restrict__ avd,
    float* __restrict__ os,            // [M][4]
    float* __restrict__ od, int M) {
    __shared__ _Float16 lds[4 * 16 * 64];
    int wave = threadIdx.x >> 6;
    int lane = threadIdx.x & 63;
    int q = lane >> 4;
    int c16 = lane & 15;
    int row0 = blockIdx.x * 64 + wave * 16;

    half8_t a[8];
    int ar = row0 + c16;
    bool avalid = (ar < M);
    const _Float16* ap = Ah + (size_t)ar * 256;
    #pragma unroll
    for (int ks = 0; ks < 8; ks++) {
        if (avalid) a[ks] = *(const half8_t*)(ap + ks * 32 + q * 8);
        else        a[ks] = (half8_t)(_Float16)0.0f;
    }

    float4_t acc[4];
    #pragma unroll
    for (int ct = 0; ct < 4; ct++) acc[ct] = (float4_t)0.f;

    #pragma unroll
    for (int ks = 0; ks < 8; ks++) {
        #pragma unroll
        for (int ct = 0; ct < 4; ct++) {
            half8_t b = *(const half8_t*)(BT + (size_t)(ct * 16 + c16) * 256 + ks * 32 + q * 8);
            acc[ct] = __builtin_amdgcn_mfma_f32_16x16x32_f16(a[ks], b, acc[ct], 0, 0, 0);
        }
    }

    float ps[4][4], pd[4][4];
    #pragma unroll
    for (int ct = 0; ct < 4; ct++) {
        float as_v = avs[ct * 16 + c16];
        float ad_v = avd[ct * 16 + c16];
        #pragma unroll
        for (int r = 0; r < 4; r++) {
            ps[ct][r] = acc[ct][r] * as_v;
            pd[ct][r] = acc[ct][r] * ad_v;
            #pragma unroll
            for (int o = 8; o >= 1; o >>= 1) {
                ps[ct][r] += __shfl_down(ps[ct][r], o, 16);
                pd[ct][r] += __shfl_down(pd[ct][r], o, 16);
            }
        }
    }
    if (c16 == 0) {
        #pragma unroll
        for (int r = 0; r < 4; r++) {
            int gr = row0 + q * 4 + r;
            if (gr < M) {
                #pragma unroll
                for (int ct = 0; ct < 4; ct++) {
                    os[(size_t)gr * HEADS + ct] = ps[ct][r];
                    od[(size_t)gr * HEADS + ct] = pd[ct][r];
                }
            }
        }
    }

    _Float16* wl = lds + wave * (16 * 64);
    #pragma unroll
    for (int ct = 0; ct < 4; ct++) {
        #pragma unroll
        for (int r = 0; r < 4; r++) {
            wl[(q * 4 + r) * 64 + ct * 16 + c16] = (_Float16)acc[ct][r];
        }
    }
    __syncthreads();
    #pragma unroll
    for (int pass = 0; pass < 2; pass++) {
        int idx8 = pass * 64 + lane;
        int row = idx8 >> 3;
        int col8 = idx8 & 7;
        int gr = row0 + row;
        if (gr < M) {
            *(half8_t*)(hout + (size_t)gr * 64 + col8 * 8) =
                *(const half8_t*)(wl + row * 64 + col8 * 8);
        }
    }
}

// ---------------- GAT aggregation layer 1 (C=64, fp16 gather, fp16 out) -----
// single-pass softmax (deg <= CAP=64); phase 2 with 16 gather rows in flight.

__global__ __launch_bounds__(256) void gat_agg64_f16_k(
    const __half* __restrict__ hsrc,  // [N, 256] fp16
    const float* __restrict__ as,     // [N, 4]
    const float* __restrict__ ad,     // [N, 4]
    const int* __restrict__ cnt,      // [N] degree (incl self-loop)
    const unsigned short* __restrict__ slots,  // [N*CAP]
    const float* __restrict__ bias,   // [256]
    __half* __restrict__ outh,        // [N, 256] fp16 (post-ReLU g1)
    int N) {
    int node = blockIdx.x * 4 + (threadIdx.x >> 6);
    if (node >= N) return;
    int l = threadIdx.x & 63;
    int h = l >> 4;
    int je = l & 15;
    int hb = h << 4;
    int deg = min(cnt[node], CAP);
    const unsigned short* sp = slots + (size_t)node * CAP;
    float adh = ad[(size_t)node * HEADS + h];
    float4 bv = *(const float4*)(bias + l * 4);

    // ---- phase 1: all e values (lane je covers edges je, je+16, je+32, je+48) ----
    int sv[4];
    float ev[4];
    #pragma unroll
    for (int k = 0; k < 4; k++) {
        int j = k * 16 + je;
        sv[k] = (j < deg) ? (int)sp[j] : 0;
    }
    #pragma unroll
    for (int k = 0; k < 4; k++) {
        int j = k * 16 + je;
        if (j < deg) {
            float a = as[(size_t)sv[k] * HEADS + h] + adh;
            ev[k] = (a > 0.f) ? a : 0.2f * a;
        } else {
            ev[k] = -INFINITY;
        }
    }
    float m = fmaxf(fmaxf(ev[0], ev[1]), fmaxf(ev[2], ev[3]));
    #pragma unroll
    for (int o = 8; o >= 1; o >>= 1) m = fmaxf(m, __shfl_xor(m, o));
    float pv[4];
    float den = 0.f;
    #pragma unroll
    for (int k = 0; k < 4; k++) {
        pv[k] = (k * 16 + je < deg) ? __expf(ev[k] - m) : 0.f;
        den += pv[k];
    }
    #pragma unroll
    for (int o = 8; o >= 1; o >>= 1) den += __shfl_xor(den, o);

    // ---- phase 2: accumulate, 16 broadcasts + 16 row-loads in flight ----
    float4 acc = make_float4(0.f, 0.f, 0.f, 0.f);
    #pragma unroll
    for (int k = 0; k < 4; k++) {
        int base = k * 16;
        if (base >= deg) break;
        int cl = min(16, deg - base);
        int sj[16];
        #pragma unroll
        for (int jj = 0; jj < 16; jj++) sj[jj] = __shfl(sv[k], hb + jj);
        uint2 rv[16];
        #pragma unroll
        for (int jj = 0; jj < 16; jj++) {
            if (jj < cl) rv[jj] = *(const uint2*)(hsrc + (size_t)sj[jj] * 256 + l * 4);
        }
        #pragma unroll
        for (int jj = 0; jj < 16; jj++) {
            if (jj < cl) {
                float pj = __shfl(pv[k], hb + jj);
                float2 a0 = __half22float2(*(__half2*)&rv[jj].x);
                float2 b0 = __half22float2(*(__half2*)&rv[jj].y);
                acc.x = fmaf(pj, a0.x, acc.x); acc.y = fmaf(pj, a0.y, acc.y);
                acc.z = fmaf(pj, b0.x, acc.z); acc.w = fmaf(pj, b0.y, acc.w);
            }
        }
    }

    float inv = 1.f / den;
    float rx = fmaxf(fmaf(acc.x, inv, bv.x), 0.f);
    float ry = fmaxf(fmaf(acc.y, inv, bv.y), 0.f);
    float rz = fmaxf(fmaf(acc.z, inv, bv.z), 0.f);
    float rw = fmaxf(fmaf(acc.w, inv, bv.w), 0.f);
    __half2* op = (__half2*)(outh + (size_t)node * 256 + l * 4);
    op[0] = __floats2half2_rn(rx, ry);
    op[1] = __floats2half2_rn(rz, rw);
}

// ---------------- GAT aggregation layer 2 (C=16, fp16 gather, MLP=4) --------

__global__ __launch_bounds__(256) void gat_agg16_f16_k(
    const __half* __restrict__ hsrc,  // [N, 64] fp16
    const float* __restrict__ as,
    const float* __restrict__ ad,
    const int* __restrict__ cnt,
    const unsigned short* __restrict__ slots,
    const float* __restrict__ bias,   // [64]
    float* __restrict__ out, int N) {
    int node = blockIdx.x * 4 + (threadIdx.x >> 6);
    if (node >= N) return;
    int l = threadIdx.x & 63;
    int ha = l >> 4;
    int je = l & 15;
    int q = l & 15;
    int hh = q >> 2;
    int eg = l >> 4;
    int deg = min(cnt[node], CAP);
    const unsigned short* sp = slots + (size_t)node * CAP;
    float adh = ad[(size_t)node * HEADS + ha];
    float m = -INFINITY, den = 0.f;
    float4 acc = make_float4(0.f, 0.f, 0.f, 0.f);
    for (int base = 0; base < deg; base += 16) {
        int cl = min(16, deg - base);
        int s = 0;
        float e = -INFINITY;
        if (je < cl) {
            s = sp[base + je];
            float a = as[(size_t)s * HEADS + ha] + adh;
            e = (a > 0.f) ? a : 0.2f * a;
        }
        float cmax = e;
        #pragma unroll
        for (int o = 8; o >= 1; o >>= 1) cmax = fmaxf(cmax, __shfl_xor(cmax, o));
        float m_new = fmaxf(m, cmax);
        float p = (je < cl) ? __expf(e - m_new) : 0.f;
        float sum = p;
        #pragma unroll
        for (int o = 8; o >= 1; o >>= 1) sum += __shfl_xor(sum, o);
        float sc = __expf(m - m_new);
        den = den * sc + sum;
        m = m_new;
        float sch = __shfl(sc, hh << 4);
        acc.x *= sch; acc.y *= sch; acc.z *= sch; acc.w *= sch;

        int jbase = eg * 4;
        float pj[4]; int sj[4]; bool vj[4];
        #pragma unroll
        for (int jj = 0; jj < 4; jj++) {
            int j = jbase + jj;
            int jc = min(j, cl - 1);
            pj[jj] = __shfl(p, (hh << 4) + jc);
            sj[jj] = __shfl(s, (hh << 4) + jc);
            vj[jj] = (j < cl);
        }
        uint2 rv[4];
        #pragma unroll
        for (int jj = 0; jj < 4; jj++) {
            if (vj[jj]) rv[jj] = *(const uint2*)(hsrc + (size_t)sj[jj] * 64 + q * 4);
        }
        #pragma unroll
        for (int jj = 0; jj < 4; jj++) {
            if (vj[jj]) {
                float2 f0 = __half22float2(*(__half2*)&rv[jj].x);
                float2 f1 = __half22float2(*(__half2*)&rv[jj].y);
                acc.x = fmaf(pj[jj], f0.x, acc.x); acc.y = fmaf(pj[jj], f0.y, acc.y);
                acc.z = fmaf(pj[jj], f1.x, acc.z); acc.w = fmaf(pj[jj], f1.y, acc.w);
            }
        }
    }
    acc.x += __shfl_xor(acc.x, 16); acc.y += __shfl_xor(acc.y, 16);
    acc.z += __shfl_xor(acc.z, 16); acc.w += __shfl_xor(acc.w, 16);
    acc.x += __shfl_xor(acc.x, 32); acc.y += __shfl_xor(acc.y, 32);
    acc.z += __shfl_xor(acc.z, 32); acc.w += __shfl_xor(acc.w, 32);
    float denh = __shfl(den, hh << 4);
    if (eg == 0) {
        float inv = 1.f / denh;
        float4 bv = *(const float4*)(bias + q * 4);
        float4 r;
        r.x = fmaxf(fmaf(acc.x, inv, bv.x), 0.f);
        r.y = fmaxf(fmaf(acc.y, inv, bv.y), 0.f);
        r.z = fmaxf(fmaf(acc.z, inv, bv.z), 0.f);
        r.w = fmaxf(fmaf(acc.w, inv, bv.w), 0.f);
        *(float4*)(out + (size_t)node * 64 + q * 4) = r;
    }
}

// ---------------- fused mean-pool + FC (one block per graph) ----------------

__global__ __launch_bounds__(256) void poolfc_k(const float* __restrict__ g2,
                                                const int* __restrict__ bstart,
                                                const float* __restrict__ w,
                                                const float* __restrict__ b,
                                                float* __restrict__ out) {
    __shared__ float red[4][64];
    __shared__ float pooled[64];
    int g = blockIdx.x;
    int lo = bstart[g], hi = bstart[g + 1];
    int c = threadIdx.x & 63;
    int r = threadIdx.x >> 6;
    float acc = 0.f;
    for (int n = lo + r; n < hi; n += 4) acc += g2[(size_t)n * 64 + c];
    red[r][c] = acc;
    __syncthreads();
    if (threadIdx.x < 64) {
        float inv = 1.f / (float)max(hi - lo, 1);
        pooled[threadIdx.x] = (red[0][threadIdx.x] + red[1][threadIdx.x] +
                               red[2][threadIdx.x] + red[3][threadIdx.x]) * inv;
    }
    __syncthreads();
    if (threadIdx.x < 32) {
        int o = threadIdx.x;
        float a = b[o];
        #pragma unroll 8
        for (int k = 0; k < 64; k++) a = fmaf(pooled[k], w[k * 32 + o], a);
        out[g * 32 + o] = a;
    }
}

// ---------------- launch ----------------

static inline size_t align_up(size_t x, size_t a) { return (x + a - 1) & ~(a - 1); }

extern "C" void kernel_launch(void* const* d_in, const int* in_sizes, int n_in,
                              void* d_out, int out_size, void* d_ws, size_t ws_size,
                              hipStream_t stream) {
    const float* x      = (const float*)d_in[0];
    const int*   ei     = (const int*)d_in[1];
    const int*   batch  = (const int*)d_in[2];
    const float* W1     = (const float*)d_in[3];
    const float* a_src1 = (const float*)d_in[4];
    const float* a_dst1 = (const float*)d_in[5];
    const float* b1     = (const float*)d_in[6];
    const float* W2     = (const float*)d_in[7];
    const float* a_src2 = (const float*)d_in[8];
    const float* a_dst2 = (const float*)d_in[9];
    const float* b2     = (const float*)d_in[10];
    const float* fc_w   = (const float*)d_in[11];
    const float* fc_b   = (const float*)d_in[12];
    float* out = (float*)d_out;

    const int N = in_sizes[2];
    const int E = in_sizes[1] / 2;
    const int F_in = in_sizes[0] / N;   // 128
    const int D1 = HEADS * 64;          // 256
    const int D2 = HEADS * 16;          // 64

    const int* src = ei;
    const int* dst = ei + E;

    char* w = (char*)d_ws;
    size_t off = 0;
    auto alloc = [&](size_t bytes) {
        size_t p = off;
        off = align_up(off + bytes, 256);
        return (void*)(w + p);
    };
    int* cnt    = (int*)alloc((size_t)N * 4);
    unsigned short* slots = (unsigned short*)alloc((size_t)N * CAP * 2);
    int* bstart = (int*)alloc(65 * 4);
    float* as1  = (float*)alloc((size_t)N * HEADS * 4);
    float* ad1  = (float*)alloc((size_t)N * HEADS * 4);
    float* as2  = (float*)alloc((size_t)N * HEADS * 4);
    float* ad2  = (float*)alloc((size_t)N * HEADS * 4);
    __half* h1h = (__half*)alloc((size_t)N * D1 * 2);
    __half* g1h = (__half*)alloc((size_t)N * D1 * 2);
    __half* h2h = (__half*)alloc((size_t)N * D2 * 2);
    float* g2   = (float*)alloc((size_t)N * D2 * 4);
    _Float16* w1t = (_Float16*)alloc((size_t)F_in * D1 * 2);  // [256][128]
    _Float16* w2t = (_Float16*)alloc((size_t)D1 * D2 * 2);    // [64][256]

    // --- merged prep: cnt/slot init + W1T + W2T + graph bounds ---
    const int NB = (N + 255) / 256;
    prep_k<<<NB + 192 + 1, 256, 0, stream>>>(cnt, slots, N, NB, W1, w1t, W2, w2t,
                                             batch, bstart);

    // --- fused: edge scatter (8-wide phased) ∥ layer-1 GEMM ---
    const int SB = (E + 2047) / 2048;        // 8 edges per scatter thread
    const int GB = (N + 63) / 64;
    fused_scatter_gemm1_k<<<SB + GB, 256, 0, stream>>>(
        src, dst, cnt, slots, E, SB,
        x, w1t, h1h, a_src1, a_dst1, as1, ad1, N);

    // --- layer 1 aggregation ---
    gat_agg64_f16_k<<<(N + 3) / 4, 256, 0, stream>>>(h1h, as1, ad1, cnt, slots, b1, g1h, N);

    // --- layer 2 ---
    mfma_gemm2_k<<<(N + 63) / 64, 256, 0, stream>>>((const _Float16*)g1h, w2t, h2h,
                                                    a_src2, a_dst2, as2, ad2, N);
    gat_agg16_f16_k<<<(N + 3) / 4, 256, 0, stream>>>(h2h, as2, ad2, cnt, slots, b2, g2, N);

    // --- fused mean-pool + fc ---
    poolfc_k<<<64, 256, 0, stream>>>(g2, bstart, fc_w, fc_b, out);
}

// Round 8
// 339.274 us; speedup vs baseline: 1.6356x; 1.0156x over previous
//
#include <hip/hip_runtime.h>
#include <hip/hip_bf16.h>
#include <hip/hip_fp16.h>
#include <math.h>

#define HEADS 4
#define CAP 64   // max in-degree incl. self-loop (Poisson(17) tail; clamped)

typedef _Float16 half8_t __attribute__((ext_vector_type(8)));
typedef float float4_t __attribute__((ext_vector_type(4)));

// -------- merged prep: cnt/slots init + W1^T fp16 + W2^T fp16 + bounds ------

__global__ __launch_bounds__(256) void prep_k(int* cnt, unsigned short* slots, int N, int NB,
                                              const float* __restrict__ W1, _Float16* __restrict__ W1T,
                                              const float* __restrict__ W2, _Float16* __restrict__ W2T,
                                              const int* __restrict__ batch, int* __restrict__ bstart) {
    int bx = blockIdx.x;
    if (bx < NB) {
        int i = bx * 256 + threadIdx.x;
        if (i < N) {
            cnt[i] = 1;
            slots[(size_t)i * CAP] = (unsigned short)i;
        }
    } else if (bx < NB + 128) {
        int k = bx - NB;           // 0..127
        int n = threadIdx.x;       // 0..255
        W1T[n * 128 + k] = (_Float16)W1[k * 256 + n];
    } else if (bx < NB + 192) {
        int n = bx - NB - 128;     // 0..63
        int k = threadIdx.x;       // 0..255
        W2T[n * 256 + k] = (_Float16)W2[k * 64 + n];
    } else {
        int t = threadIdx.x;
        if (t <= 64) {
            int lo = 0, hi = N;
            while (lo < hi) {
                int mid = (lo + hi) >> 1;
                if (batch[mid] < t) lo = mid + 1; else hi = mid;
            }
            bstart[t] = lo;
        }
    }
}

// ---------------- fused: edge scatter (8-wide phased MLP) ∥ MFMA GEMM1 ------

__global__ __launch_bounds__(256) void fused_scatter_gemm1_k(
    const int* __restrict__ src, const int* __restrict__ dst,
    int* __restrict__ cnt, unsigned short* __restrict__ slots, int E, int SB,
    const float* __restrict__ A,       // [M][128] fp32 (x)
    const _Float16* __restrict__ BT,   // [256][128] (W1^T)
    __half* __restrict__ hout,         // [M][256] fp16
    const float* __restrict__ avs,     // [4][64]
    const float* __restrict__ avd,
    float* __restrict__ os,            // [M][4]
    float* __restrict__ od, int M) {
    __shared__ _Float16 lds[4 * 16 * 72];   // 9 KB; per-wave 16x64 chunk (stride 72)

    if ((int)blockIdx.x < SB) {
        // ---- scatter branch: 8 edges per thread, phased for MLP ----
        int T = SB * 256;
        int t0 = blockIdx.x * 256 + threadIdx.x;
        int d[8], s[8];
        #pragma unroll
        for (int k = 0; k < 8; k++) {
            int i = t0 + k * T;
            if (i < E) { d[k] = dst[i]; s[k] = src[i]; }
            else d[k] = -1;
        }
        int p[8];
        #pragma unroll
        for (int k = 0; k < 8; k++) {
            if (d[k] >= 0) p[k] = atomicAdd(&cnt[d[k]], 1);
        }
        #pragma unroll
        for (int k = 0; k < 8; k++) {
            if (d[k] >= 0 && p[k] < CAP)
                slots[(size_t)d[k] * CAP + p[k]] = (unsigned short)s[k];
        }
        return;
    }

    // ---- GEMM1 branch ----
    int bx = blockIdx.x - SB;
    int wave = threadIdx.x >> 6;
    int lane = threadIdx.x & 63;
    int q = lane >> 4;
    int c16 = lane & 15;
    int row0 = bx * 64 + wave * 16;

    half8_t a[4];
    int ar = row0 + c16;
    bool avalid = (ar < M);
    const float* ap = A + (size_t)ar * 128;
    #pragma unroll
    for (int ks = 0; ks < 4; ks++) {
        if (avalid) {
            float4 f0 = *(const float4*)(ap + ks * 32 + q * 8);
            float4 f1 = *(const float4*)(ap + ks * 32 + q * 8 + 4);
            half8_t h;
            h[0] = (_Float16)f0.x; h[1] = (_Float16)f0.y;
            h[2] = (_Float16)f0.z; h[3] = (_Float16)f0.w;
            h[4] = (_Float16)f1.x; h[5] = (_Float16)f1.y;
            h[6] = (_Float16)f1.z; h[7] = (_Float16)f1.w;
            a[ks] = h;
        } else {
            a[ks] = (half8_t)(_Float16)0.0f;
        }
    }

    float4_t acc[16];
    #pragma unroll
    for (int ct = 0; ct < 16; ct++) acc[ct] = (float4_t)0.f;

    #pragma unroll
    for (int ks = 0; ks < 4; ks++) {
        #pragma unroll
        for (int ct = 0; ct < 16; ct++) {
            half8_t b = *(const half8_t*)(BT + (size_t)(ct * 16 + c16) * 128 + ks * 32 + q * 8);
            acc[ct] = __builtin_amdgcn_mfma_f32_16x16x32_f16(a[ks], b, acc[ct], 0, 0, 0);
        }
    }

    // alpha dot partials (head h = ct>>2, chan-in-head = (ct&3)*16 + c16)
    float psh[4][4] = {}, pdh[4][4] = {};
    #pragma unroll
    for (int ct = 0; ct < 16; ct++) {
        int h = ct >> 2;
        int cih = (ct & 3) * 16 + c16;
        float as_v = avs[h * 64 + cih];
        float ad_v = avd[h * 64 + cih];
        #pragma unroll
        for (int r = 0; r < 4; r++) {
            psh[h][r] = fmaf(acc[ct][r], as_v, psh[h][r]);
            pdh[h][r] = fmaf(acc[ct][r], ad_v, pdh[h][r]);
        }
    }
    #pragma unroll
    for (int h = 0; h < 4; h++) {
        #pragma unroll
        for (int r = 0; r < 4; r++) {
            #pragma unroll
            for (int o = 8; o >= 1; o >>= 1) {
                psh[h][r] += __shfl_down(psh[h][r], o, 16);
                pdh[h][r] += __shfl_down(pdh[h][r], o, 16);
            }
        }
    }
    if (c16 == 0) {
        #pragma unroll
        for (int r = 0; r < 4; r++) {
            int gr = row0 + q * 4 + r;
            if (gr < M) {
                #pragma unroll
                for (int h = 0; h < 4; h++) {
                    os[(size_t)gr * HEADS + h] = psh[h][r];
                    od[(size_t)gr * HEADS + h] = pdh[h][r];
                }
            }
        }
    }

    // fp16 store via per-wave chunked LDS staging (stride 72 halfs = 144 B)
    _Float16* wl = lds + wave * (16 * 72);
    #pragma unroll
    for (int chunk = 0; chunk < 4; chunk++) {
        #pragma unroll
        for (int c4 = 0; c4 < 4; c4++) {
            int ct = chunk * 4 + c4;
            #pragma unroll
            for (int r = 0; r < 4; r++) {
                wl[(q * 4 + r) * 72 + c4 * 16 + c16] = (_Float16)acc[ct][r];
            }
        }
        __syncthreads();
        #pragma unroll
        for (int pass = 0; pass < 2; pass++) {
            int idx8 = pass * 64 + lane;   // 128 half8 units (16 rows x 8)
            int row = idx8 >> 3;
            int col8 = idx8 & 7;
            int gr = row0 + row;
            if (gr < M) {
                *(half8_t*)(hout + (size_t)gr * 256 + chunk * 64 + col8 * 8) =
                    *(const half8_t*)(wl + row * 72 + col8 * 8);
            }
        }
        __syncthreads();
    }
}

// ---------------- MFMA GEMM layer 2: h2 = g1 @ W2 ----------------

__global__ __launch_bounds__(256) void mfma_gemm2_k(
    const _Float16* __restrict__ Ah,   // [M][256] fp16 (g1)
    const _Float16* __restrict__ BT,   // [64][256] (W2^T)
    __half* __restrict__ hout,         // [M][64] fp16
    const float* __restrict__ avs,     // [4][16]
    const float* __restrict__ avd,
    float* __restrict__ os,            // [M][4]
    float* __restrict__ od, int M) {
    __shared__ _Float16 lds[4 * 16 * 64];
    int wave = threadIdx.x >> 6;
    int lane = threadIdx.x & 63;
    int q = lane >> 4;
    int c16 = lane & 15;
    int row0 = blockIdx.x * 64 + wave * 16;

    half8_t a[8];
    int ar = row0 + c16;
    bool avalid = (ar < M);
    const _Float16* ap = Ah + (size_t)ar * 256;
    #pragma unroll
    for (int ks = 0; ks < 8; ks++) {
        if (avalid) a[ks] = *(const half8_t*)(ap + ks * 32 + q * 8);
        else        a[ks] = (half8_t)(_Float16)0.0f;
    }

    float4_t acc[4];
    #pragma unroll
    for (int ct = 0; ct < 4; ct++) acc[ct] = (float4_t)0.f;

    #pragma unroll
    for (int ks = 0; ks < 8; ks++) {
        #pragma unroll
        for (int ct = 0; ct < 4; ct++) {
            half8_t b = *(const half8_t*)(BT + (size_t)(ct * 16 + c16) * 256 + ks * 32 + q * 8);
            acc[ct] = __builtin_amdgcn_mfma_f32_16x16x32_f16(a[ks], b, acc[ct], 0, 0, 0);
        }
    }

    float ps[4][4], pd[4][4];
    #pragma unroll
    for (int ct = 0; ct < 4; ct++) {
        float as_v = avs[ct * 16 + c16];
        float ad_v = avd[ct * 16 + c16];
        #pragma unroll
        for (int r = 0; r < 4; r++) {
            ps[ct][r] = acc[ct][r] * as_v;
            pd[ct][r] = acc[ct][r] * ad_v;
            #pragma unroll
            for (int o = 8; o >= 1; o >>= 1) {
                ps[ct][r] += __shfl_down(ps[ct][r], o, 16);
                pd[ct][r] += __shfl_down(pd[ct][r], o, 16);
            }
        }
    }
    if (c16 == 0) {
        #pragma unroll
        for (int r = 0; r < 4; r++) {
            int gr = row0 + q * 4 + r;
            if (gr < M) {
                #pragma unroll
                for (int ct = 0; ct < 4; ct++) {
                    os[(size_t)gr * HEADS + ct] = ps[ct][r];
                    od[(size_t)gr * HEADS + ct] = pd[ct][r];
                }
            }
        }
    }

    _Float16* wl = lds + wave * (16 * 64);
    #pragma unroll
    for (int ct = 0; ct < 4; ct++) {
        #pragma unroll
        for (int r = 0; r < 4; r++) {
            wl[(q * 4 + r) * 64 + ct * 16 + c16] = (_Float16)acc[ct][r];
        }
    }
    __syncthreads();
    #pragma unroll
    for (int pass = 0; pass < 2; pass++) {
        int idx8 = pass * 64 + lane;
        int row = idx8 >> 3;
        int col8 = idx8 & 7;
        int gr = row0 + row;
        if (gr < M) {
            *(half8_t*)(hout + (size_t)gr * 64 + col8 * 8) =
                *(const half8_t*)(wl + row * 64 + col8 * 8);
        }
    }
}

// ---------------- GAT aggregation layer 1 (C=64, fp16 gather, fp16 out) -----
// single-pass softmax (deg <= CAP=64), 8 gather rows in flight per wave
// (R3-proven operating point; 16-deep regressed via VGPR/occupancy in R7).

__global__ __launch_bounds__(256) void gat_agg64_f16_k(
    const __half* __restrict__ hsrc,  // [N, 256] fp16
    const float* __restrict__ as,     // [N, 4]
    const float* __restrict__ ad,     // [N, 4]
    const int* __restrict__ cnt,      // [N] degree (incl self-loop)
    const unsigned short* __restrict__ slots,  // [N*CAP]
    const float* __restrict__ bias,   // [256]
    __half* __restrict__ outh,        // [N, 256] fp16 (post-ReLU g1)
    int N) {
    int node = blockIdx.x * 4 + (threadIdx.x >> 6);
    if (node >= N) return;
    int l = threadIdx.x & 63;
    int h = l >> 4;
    int je = l & 15;
    int hb = h << 4;
    int deg = min(cnt[node], CAP);
    const unsigned short* sp = slots + (size_t)node * CAP;
    float adh = ad[(size_t)node * HEADS + h];
    float4 bv = *(const float4*)(bias + l * 4);

    // ---- phase 1: all e values (lane je covers edges je, je+16, je+32, je+48) ----
    int sv[4];
    float ev[4];
    #pragma unroll
    for (int k = 0; k < 4; k++) {
        int j = k * 16 + je;
        sv[k] = (j < deg) ? (int)sp[j] : 0;
    }
    #pragma unroll
    for (int k = 0; k < 4; k++) {
        int j = k * 16 + je;
        if (j < deg) {
            float a = as[(size_t)sv[k] * HEADS + h] + adh;
            ev[k] = (a > 0.f) ? a : 0.2f * a;
        } else {
            ev[k] = -INFINITY;
        }
    }
    float m = fmaxf(fmaxf(ev[0], ev[1]), fmaxf(ev[2], ev[3]));
    #pragma unroll
    for (int o = 8; o >= 1; o >>= 1) m = fmaxf(m, __shfl_xor(m, o));
    float pv[4];
    float den = 0.f;
    #pragma unroll
    for (int k = 0; k < 4; k++) {
        pv[k] = (k * 16 + je < deg) ? __expf(ev[k] - m) : 0.f;
        den += pv[k];
    }
    #pragma unroll
    for (int o = 8; o >= 1; o >>= 1) den += __shfl_xor(den, o);

    // ---- phase 2: accumulate, 8 broadcasts + 8 row-loads in flight ----
    float4 acc = make_float4(0.f, 0.f, 0.f, 0.f);
    #pragma unroll
    for (int k = 0; k < 4; k++) {
        int base = k * 16;
        if (base >= deg) break;
        int cl = min(16, deg - base);
        #pragma unroll
        for (int half = 0; half < 2; half++) {
            int j0 = half * 8;
            if (j0 >= cl) break;
            float pj[8]; int sj[8];
            #pragma unroll
            for (int jj = 0; jj < 8; jj++) {
                pj[jj] = __shfl(pv[k], hb + j0 + jj);
                sj[jj] = __shfl(sv[k], hb + j0 + jj);
            }
            uint2 rv[8];
            #pragma unroll
            for (int jj = 0; jj < 8; jj++) {
                if (j0 + jj < cl) rv[jj] = *(const uint2*)(hsrc + (size_t)sj[jj] * 256 + l * 4);
            }
            #pragma unroll
            for (int jj = 0; jj < 8; jj++) {
                if (j0 + jj < cl) {
                    float2 a0 = __half22float2(*(__half2*)&rv[jj].x);
                    float2 b0 = __half22float2(*(__half2*)&rv[jj].y);
                    acc.x = fmaf(pj[jj], a0.x, acc.x); acc.y = fmaf(pj[jj], a0.y, acc.y);
                    acc.z = fmaf(pj[jj], b0.x, acc.z); acc.w = fmaf(pj[jj], b0.y, acc.w);
                }
            }
        }
    }

    float inv = 1.f / den;
    float rx = fmaxf(fmaf(acc.x, inv, bv.x), 0.f);
    float ry = fmaxf(fmaf(acc.y, inv, bv.y), 0.f);
    float rz = fmaxf(fmaf(acc.z, inv, bv.z), 0.f);
    float rw = fmaxf(fmaf(acc.w, inv, bv.w), 0.f);
    __half2* op = (__half2*)(outh + (size_t)node * 256 + l * 4);
    op[0] = __floats2half2_rn(rx, ry);
    op[1] = __floats2half2_rn(rz, rw);
}

// ---------------- GAT aggregation layer 2 (C=16, fp16 gather, MLP=4) --------

__global__ __launch_bounds__(256) void gat_agg16_f16_k(
    const __half* __restrict__ hsrc,  // [N, 64] fp16
    const float* __restrict__ as,
    const float* __restrict__ ad,
    const int* __restrict__ cnt,
    const unsigned short* __restrict__ slots,
    const float* __restrict__ bias,   // [64]
    float* __restrict__ out, int N) {
    int node = blockIdx.x * 4 + (threadIdx.x >> 6);
    if (node >= N) return;
    int l = threadIdx.x & 63;
    int ha = l >> 4;
    int je = l & 15;
    int q = l & 15;
    int hh = q >> 2;
    int eg = l >> 4;
    int deg = min(cnt[node], CAP);
    const unsigned short* sp = slots + (size_t)node * CAP;
    float adh = ad[(size_t)node * HEADS + ha];
    float m = -INFINITY, den = 0.f;
    float4 acc = make_float4(0.f, 0.f, 0.f, 0.f);
    for (int base = 0; base < deg; base += 16) {
        int cl = min(16, deg - base);
        int s = 0;
        float e = -INFINITY;
        if (je < cl) {
            s = sp[base + je];
            float a = as[(size_t)s * HEADS + ha] + adh;
            e = (a > 0.f) ? a : 0.2f * a;
        }
        float cmax = e;
        #pragma unroll
        for (int o = 8; o >= 1; o >>= 1) cmax = fmaxf(cmax, __shfl_xor(cmax, o));
        float m_new = fmaxf(m, cmax);
        float p = (je < cl) ? __expf(e - m_new) : 0.f;
        float sum = p;
        #pragma unroll
        for (int o = 8; o >= 1; o >>= 1) sum += __shfl_xor(sum, o);
        float sc = __expf(m - m_new);
        den = den * sc + sum;
        m = m_new;
        float sch = __shfl(sc, hh << 4);
        acc.x *= sch; acc.y *= sch; acc.z *= sch; acc.w *= sch;

        int jbase = eg * 4;
        float pj[4]; int sj[4]; bool vj[4];
        #pragma unroll
        for (int jj = 0; jj < 4; jj++) {
            int j = jbase + jj;
            int jc = min(j, cl - 1);
            pj[jj] = __shfl(p, (hh << 4) + jc);
            sj[jj] = __shfl(s, (hh << 4) + jc);
            vj[jj] = (j < cl);
        }
        uint2 rv[4];
        #pragma unroll
        for (int jj = 0; jj < 4; jj++) {
            if (vj[jj]) rv[jj] = *(const uint2*)(hsrc + (size_t)sj[jj] * 64 + q * 4);
        }
        #pragma unroll
        for (int jj = 0; jj < 4; jj++) {
            if (vj[jj]) {
                float2 f0 = __half22float2(*(__half2*)&rv[jj].x);
                float2 f1 = __half22float2(*(__half2*)&rv[jj].y);
                acc.x = fmaf(pj[jj], f0.x, acc.x); acc.y = fmaf(pj[jj], f0.y, acc.y);
                acc.z = fmaf(pj[jj], f1.x, acc.z); acc.w = fmaf(pj[jj], f1.y, acc.w);
            }
        }
    }
    acc.x += __shfl_xor(acc.x, 16); acc.y += __shfl_xor(acc.y, 16);
    acc.z += __shfl_xor(acc.z, 16); acc.w += __shfl_xor(acc.w, 16);
    acc.x += __shfl_xor(acc.x, 32); acc.y += __shfl_xor(acc.y, 32);
    acc.z += __shfl_xor(acc.z, 32); acc.w += __shfl_xor(acc.w, 32);
    float denh = __shfl(den, hh << 4);
    if (eg == 0) {
        float inv = 1.f / denh;
        float4 bv = *(const float4*)(bias + q * 4);
        float4 r;
        r.x = fmaxf(fmaf(acc.x, inv, bv.x), 0.f);
        r.y = fmaxf(fmaf(acc.y, inv, bv.y), 0.f);
        r.z = fmaxf(fmaf(acc.z, inv, bv.z), 0.f);
        r.w = fmaxf(fmaf(acc.w, inv, bv.w), 0.f);
        *(float4*)(out + (size_t)node * 64 + q * 4) = r;
    }
}

// ---------------- fused mean-pool + FC (one block per graph) ----------------

__global__ __launch_bounds__(256) void poolfc_k(const float* __restrict__ g2,
                                                const int* __restrict__ bstart,
                                                const float* __restrict__ w,
                                                const float* __restrict__ b,
                                                float* __restrict__ out) {
    __shared__ float red[4][64];
    __shared__ float pooled[64];
    int g = blockIdx.x;
    int lo = bstart[g], hi = bstart[g + 1];
    int c = threadIdx.x & 63;
    int r = threadIdx.x >> 6;
    float acc = 0.f;
    for (int n = lo + r; n < hi; n += 4) acc += g2[(size_t)n * 64 + c];
    red[r][c] = acc;
    __syncthreads();
    if (threadIdx.x < 64) {
        float inv = 1.f / (float)max(hi - lo, 1);
        pooled[threadIdx.x] = (red[0][threadIdx.x] + red[1][threadIdx.x] +
                               red[2][threadIdx.x] + red[3][threadIdx.x]) * inv;
    }
    __syncthreads();
    if (threadIdx.x < 32) {
        int o = threadIdx.x;
        float a = b[o];
        #pragma unroll 8
        for (int k = 0; k < 64; k++) a = fmaf(pooled[k], w[k * 32 + o], a);
        out[g * 32 + o] = a;
    }
}

// ---------------- launch ----------------

static inline size_t align_up(size_t x, size_t a) { return (x + a - 1) & ~(a - 1); }

extern "C" void kernel_launch(void* const* d_in, const int* in_sizes, int n_in,
                              void* d_out, int out_size, void* d_ws, size_t ws_size,
                              hipStream_t stream) {
    const float* x      = (const float*)d_in[0];
    const int*   ei     = (const int*)d_in[1];
    const int*   batch  = (const int*)d_in[2];
    const float* W1     = (const float*)d_in[3];
    const float* a_src1 = (const float*)d_in[4];
    const float* a_dst1 = (const float*)d_in[5];
    const float* b1     = (const float*)d_in[6];
    const float* W2     = (const float*)d_in[7];
    const float* a_src2 = (const float*)d_in[8];
    const float* a_dst2 = (const float*)d_in[9];
    const float* b2     = (const float*)d_in[10];
    const float* fc_w   = (const float*)d_in[11];
    const float* fc_b   = (const float*)d_in[12];
    float* out = (float*)d_out;

    const int N = in_sizes[2];
    const int E = in_sizes[1] / 2;
    const int F_in = in_sizes[0] / N;   // 128
    const int D1 = HEADS * 64;          // 256
    const int D2 = HEADS * 16;          // 64

    const int* src = ei;
    const int* dst = ei + E;

    char* w = (char*)d_ws;
    size_t off = 0;
    auto alloc = [&](size_t bytes) {
        size_t p = off;
        off = align_up(off + bytes, 256);
        return (void*)(w + p);
    };
    int* cnt    = (int*)alloc((size_t)N * 4);
    unsigned short* slots = (unsigned short*)alloc((size_t)N * CAP * 2);
    int* bstart = (int*)alloc(65 * 4);
    float* as1  = (float*)alloc((size_t)N * HEADS * 4);
    float* ad1  = (float*)alloc((size_t)N * HEADS * 4);
    float* as2  = (float*)alloc((size_t)N * HEADS * 4);
    float* ad2  = (float*)alloc((size_t)N * HEADS * 4);
    __half* h1h = (__half*)alloc((size_t)N * D1 * 2);
    __half* g1h = (__half*)alloc((size_t)N * D1 * 2);
    __half* h2h = (__half*)alloc((size_t)N * D2 * 2);
    float* g2   = (float*)alloc((size_t)N * D2 * 4);
    _Float16* w1t = (_Float16*)alloc((size_t)F_in * D1 * 2);  // [256][128]
    _Float16* w2t = (_Float16*)alloc((size_t)D1 * D2 * 2);    // [64][256]

    // --- merged prep: cnt/slot init + W1T + W2T + graph bounds ---
    const int NB = (N + 255) / 256;
    prep_k<<<NB + 192 + 1, 256, 0, stream>>>(cnt, slots, N, NB, W1, w1t, W2, w2t,
                                             batch, bstart);

    // --- fused: edge scatter (8-wide phased) ∥ layer-1 GEMM ---
    const int SB = (E + 2047) / 2048;        // 8 edges per scatter thread
    const int GB = (N + 63) / 64;
    fused_scatter_gemm1_k<<<SB + GB, 256, 0, stream>>>(
        src, dst, cnt, slots, E, SB,
        x, w1t, h1h, a_src1, a_dst1, as1, ad1, N);

    // --- layer 1 aggregation ---
    gat_agg64_f16_k<<<(N + 3) / 4, 256, 0, stream>>>(h1h, as1, ad1, cnt, slots, b1, g1h, N);

    // --- layer 2 ---
    mfma_gemm2_k<<<(N + 63) / 64, 256, 0, stream>>>((const _Float16*)g1h, w2t, h2h,
                                                    a_src2, a_dst2, as2, ad2, N);
    gat_agg16_f16_k<<<(N + 3) / 4, 256, 0, stream>>>(h2h, as2, ad2, cnt, slots, b2, g2, N);

    // --- fused mean-pool + fc ---
    poolfc_k<<<64, 256, 0, stream>>>(g2, bstart, fc_w, fc_b, out);
}

// Round 9
// 313.515 us; speedup vs baseline: 1.7699x; 1.0822x over previous
//
#include <hip/hip_runtime.h>
#include <hip/hip_bf16.h>
#include <hip/hip_fp16.h>
#include <math.h>

#define HEADS 4
#define CAP 64    // max in-degree incl. self-loop (Poisson(17) tail; clamped)
#define CS 16     // cnt stride in ints: one counter per 64B line

typedef _Float16 half8_t __attribute__((ext_vector_type(8)));
typedef float float4_t __attribute__((ext_vector_type(4)));

// -------- merged prep: cnt/slots init + W1^T fp16 + W2^T fp16 ---------------

__global__ __launch_bounds__(256) void prep_k(int* cnt, unsigned short* slots, int N, int NB,
                                              const float* __restrict__ W1, _Float16* __restrict__ W1T,
                                              const float* __restrict__ W2, _Float16* __restrict__ W2T) {
    int bx = blockIdx.x;
    if (bx < NB) {
        int i = bx * 256 + threadIdx.x;
        if (i < N) {
            cnt[(size_t)i * CS] = 1;
            slots[(size_t)i * CAP] = (unsigned short)i;
        }
    } else if (bx < NB + 128) {
        int k = bx - NB;           // 0..127
        int n = threadIdx.x;       // 0..255
        W1T[n * 128 + k] = (_Float16)W1[k * 256 + n];
    } else {
        int n = bx - NB - 128;     // 0..63
        int k = threadIdx.x;       // 0..255
        W2T[n * 256 + k] = (_Float16)W2[k * 64 + n];
    }
}

// ---------------- fused: edge scatter (8-wide phased MLP) ∥ MFMA GEMM1 ------

__global__ __launch_bounds__(256) void fused_scatter_gemm1_k(
    const int* __restrict__ src, const int* __restrict__ dst,
    int* __restrict__ cnt, unsigned short* __restrict__ slots, int E, int SB,
    const float* __restrict__ A,       // [M][128] fp32 (x)
    const _Float16* __restrict__ BT,   // [256][128] (W1^T)
    __half* __restrict__ hout,         // [M][256] fp16
    const float* __restrict__ avs,     // [4][64]
    const float* __restrict__ avd,
    float* __restrict__ os,            // [M][4]
    float* __restrict__ od, int M) {
    __shared__ _Float16 lds[4 * 16 * 72];   // 9 KB; per-wave 16x64 chunk (stride 72)

    if ((int)blockIdx.x < SB) {
        // ---- scatter branch: 8 edges per thread, phased for MLP ----
        int T = SB * 256;
        int t0 = blockIdx.x * 256 + threadIdx.x;
        int d[8], s[8];
        #pragma unroll
        for (int k = 0; k < 8; k++) {
            int i = t0 + k * T;
            if (i < E) { d[k] = dst[i]; s[k] = src[i]; }
            else d[k] = -1;
        }
        int p[8];
        #pragma unroll
        for (int k = 0; k < 8; k++) {
            if (d[k] >= 0) p[k] = atomicAdd(&cnt[(size_t)d[k] * CS], 1);
        }
        #pragma unroll
        for (int k = 0; k < 8; k++) {
            if (d[k] >= 0 && p[k] < CAP)
                slots[(size_t)d[k] * CAP + p[k]] = (unsigned short)s[k];
        }
        return;
    }

    // ---- GEMM1 branch ----
    int bx = blockIdx.x - SB;
    int wave = threadIdx.x >> 6;
    int lane = threadIdx.x & 63;
    int q = lane >> 4;
    int c16 = lane & 15;
    int row0 = bx * 64 + wave * 16;

    half8_t a[4];
    int ar = row0 + c16;
    bool avalid = (ar < M);
    const float* ap = A + (size_t)ar * 128;
    #pragma unroll
    for (int ks = 0; ks < 4; ks++) {
        if (avalid) {
            float4 f0 = *(const float4*)(ap + ks * 32 + q * 8);
            float4 f1 = *(const float4*)(ap + ks * 32 + q * 8 + 4);
            half8_t h;
            h[0] = (_Float16)f0.x; h[1] = (_Float16)f0.y;
            h[2] = (_Float16)f0.z; h[3] = (_Float16)f0.w;
            h[4] = (_Float16)f1.x; h[5] = (_Float16)f1.y;
            h[6] = (_Float16)f1.z; h[7] = (_Float16)f1.w;
            a[ks] = h;
        } else {
            a[ks] = (half8_t)(_Float16)0.0f;
        }
    }

    float4_t acc[16];
    #pragma unroll
    for (int ct = 0; ct < 16; ct++) acc[ct] = (float4_t)0.f;

    #pragma unroll
    for (int ks = 0; ks < 4; ks++) {
        #pragma unroll
        for (int ct = 0; ct < 16; ct++) {
            half8_t b = *(const half8_t*)(BT + (size_t)(ct * 16 + c16) * 128 + ks * 32 + q * 8);
            acc[ct] = __builtin_amdgcn_mfma_f32_16x16x32_f16(a[ks], b, acc[ct], 0, 0, 0);
        }
    }

    // alpha dot partials (head h = ct>>2, chan-in-head = (ct&3)*16 + c16)
    float psh[4][4] = {}, pdh[4][4] = {};
    #pragma unroll
    for (int ct = 0; ct < 16; ct++) {
        int h = ct >> 2;
        int cih = (ct & 3) * 16 + c16;
        float as_v = avs[h * 64 + cih];
        float ad_v = avd[h * 64 + cih];
        #pragma unroll
        for (int r = 0; r < 4; r++) {
            psh[h][r] = fmaf(acc[ct][r], as_v, psh[h][r]);
            pdh[h][r] = fmaf(acc[ct][r], ad_v, pdh[h][r]);
        }
    }
    #pragma unroll
    for (int h = 0; h < 4; h++) {
        #pragma unroll
        for (int r = 0; r < 4; r++) {
            #pragma unroll
            for (int o = 8; o >= 1; o >>= 1) {
                psh[h][r] += __shfl_down(psh[h][r], o, 16);
                pdh[h][r] += __shfl_down(pdh[h][r], o, 16);
            }
        }
    }
    if (c16 == 0) {
        #pragma unroll
        for (int r = 0; r < 4; r++) {
            int gr = row0 + q * 4 + r;
            if (gr < M) {
                #pragma unroll
                for (int h = 0; h < 4; h++) {
                    os[(size_t)gr * HEADS + h] = psh[h][r];
                    od[(size_t)gr * HEADS + h] = pdh[h][r];
                }
            }
        }
    }

    // fp16 store via per-wave chunked LDS staging (stride 72 halfs = 144 B)
    _Float16* wl = lds + wave * (16 * 72);
    #pragma unroll
    for (int chunk = 0; chunk < 4; chunk++) {
        #pragma unroll
        for (int c4 = 0; c4 < 4; c4++) {
            int ct = chunk * 4 + c4;
            #pragma unroll
            for (int r = 0; r < 4; r++) {
                wl[(q * 4 + r) * 72 + c4 * 16 + c16] = (_Float16)acc[ct][r];
            }
        }
        __syncthreads();
        #pragma unroll
        for (int pass = 0; pass < 2; pass++) {
            int idx8 = pass * 64 + lane;   // 128 half8 units (16 rows x 8)
            int row = idx8 >> 3;
            int col8 = idx8 & 7;
            int gr = row0 + row;
            if (gr < M) {
                *(half8_t*)(hout + (size_t)gr * 256 + chunk * 64 + col8 * 8) =
                    *(const half8_t*)(wl + row * 72 + col8 * 8);
            }
        }
        __syncthreads();
    }
}

// ---------------- MFMA GEMM layer 2: h2 = g1 @ W2 ----------------

__global__ __launch_bounds__(256) void mfma_gemm2_k(
    const _Float16* __restrict__ Ah,   // [M][256] fp16 (g1)
    const _Float16* __restrict__ BT,   // [64][256] (W2^T)
    __half* __restrict__ hout,         // [M][64] fp16
    const float* __restrict__ avs,     // [4][16]
    const float* __restrict__ avd,
    float* __restrict__ os,            // [M][4]
    float* __restrict__ od, int M) {
    __shared__ _Float16 lds[4 * 16 * 64];
    int wave = threadIdx.x >> 6;
    int lane = threadIdx.x & 63;
    int q = lane >> 4;
    int c16 = lane & 15;
    int row0 = blockIdx.x * 64 + wave * 16;

    half8_t a[8];
    int ar = row0 + c16;
    bool avalid = (ar < M);
    const _Float16* ap = Ah + (size_t)ar * 256;
    #pragma unroll
    for (int ks = 0; ks < 8; ks++) {
        if (avalid) a[ks] = *(const half8_t*)(ap + ks * 32 + q * 8);
        else        a[ks] = (half8_t)(_Float16)0.0f;
    }

    float4_t acc[4];
    #pragma unroll
    for (int ct = 0; ct < 4; ct++) acc[ct] = (float4_t)0.f;

    #pragma unroll
    for (int ks = 0; ks < 8; ks++) {
        #pragma unroll
        for (int ct = 0; ct < 4; ct++) {
            half8_t b = *(const half8_t*)(BT + (size_t)(ct * 16 + c16) * 256 + ks * 32 + q * 8);
            acc[ct] = __builtin_amdgcn_mfma_f32_16x16x32_f16(a[ks], b, acc[ct], 0, 0, 0);
        }
    }

    float ps[4][4], pd[4][4];
    #pragma unroll
    for (int ct = 0; ct < 4; ct++) {
        float as_v = avs[ct * 16 + c16];
        float ad_v = avd[ct * 16 + c16];
        #pragma unroll
        for (int r = 0; r < 4; r++) {
            ps[ct][r] = acc[ct][r] * as_v;
            pd[ct][r] = acc[ct][r] * ad_v;
            #pragma unroll
            for (int o = 8; o >= 1; o >>= 1) {
                ps[ct][r] += __shfl_down(ps[ct][r], o, 16);
                pd[ct][r] += __shfl_down(pd[ct][r], o, 16);
            }
        }
    }
    if (c16 == 0) {
        #pragma unroll
        for (int r = 0; r < 4; r++) {
            int gr = row0 + q * 4 + r;
            if (gr < M) {
                #pragma unroll
                for (int ct = 0; ct < 4; ct++) {
                    os[(size_t)gr * HEADS + ct] = ps[ct][r];
                    od[(size_t)gr * HEADS + ct] = pd[ct][r];
                }
            }
        }
    }

    _Float16* wl = lds + wave * (16 * 64);
    #pragma unroll
    for (int ct = 0; ct < 4; ct++) {
        #pragma unroll
        for (int r = 0; r < 4; r++) {
            wl[(q * 4 + r) * 64 + ct * 16 + c16] = (_Float16)acc[ct][r];
        }
    }
    __syncthreads();
    #pragma unroll
    for (int pass = 0; pass < 2; pass++) {
        int idx8 = pass * 64 + lane;
        int row = idx8 >> 3;
        int col8 = idx8 & 7;
        int gr = row0 + row;
        if (gr < M) {
            *(half8_t*)(hout + (size_t)gr * 64 + col8 * 8) =
                *(const half8_t*)(wl + row * 64 + col8 * 8);
        }
    }
}

// ---------------- GAT aggregation layer 1 (C=64, fp16 gather, fp16 out) -----
// single-pass softmax (deg <= CAP=64), 8 gather rows in flight per wave.

__global__ __launch_bounds__(256) void gat_agg64_f16_k(
    const __half* __restrict__ hsrc,  // [N, 256] fp16
    const float* __restrict__ as,     // [N, 4]
    const float* __restrict__ ad,     // [N, 4]
    const int* __restrict__ cnt,      // [N*CS] degree (incl self-loop), strided
    const unsigned short* __restrict__ slots,  // [N*CAP]
    const float* __restrict__ bias,   // [256]
    __half* __restrict__ outh,        // [N, 256] fp16 (post-ReLU g1)
    int N) {
    int node = blockIdx.x * 4 + (threadIdx.x >> 6);
    if (node >= N) return;
    int l = threadIdx.x & 63;
    int h = l >> 4;
    int je = l & 15;
    int hb = h << 4;
    int deg = min(cnt[(size_t)node * CS], CAP);
    const unsigned short* sp = slots + (size_t)node * CAP;
    float adh = ad[(size_t)node * HEADS + h];
    float4 bv = *(const float4*)(bias + l * 4);

    // ---- phase 1: all e values (lane je covers edges je, je+16, je+32, je+48) ----
    int sv[4];
    float ev[4];
    #pragma unroll
    for (int k = 0; k < 4; k++) {
        int j = k * 16 + je;
        sv[k] = (j < deg) ? (int)sp[j] : 0;
    }
    #pragma unroll
    for (int k = 0; k < 4; k++) {
        int j = k * 16 + je;
        if (j < deg) {
            float a = as[(size_t)sv[k] * HEADS + h] + adh;
            ev[k] = (a > 0.f) ? a : 0.2f * a;
        } else {
            ev[k] = -INFINITY;
        }
    }
    float m = fmaxf(fmaxf(ev[0], ev[1]), fmaxf(ev[2], ev[3]));
    #pragma unroll
    for (int o = 8; o >= 1; o >>= 1) m = fmaxf(m, __shfl_xor(m, o));
    float pv[4];
    float den = 0.f;
    #pragma unroll
    for (int k = 0; k < 4; k++) {
        pv[k] = (k * 16 + je < deg) ? __expf(ev[k] - m) : 0.f;
        den += pv[k];
    }
    #pragma unroll
    for (int o = 8; o >= 1; o >>= 1) den += __shfl_xor(den, o);

    // ---- phase 2: accumulate, 8 broadcasts + 8 row-loads in flight ----
    float4 acc = make_float4(0.f, 0.f, 0.f, 0.f);
    #pragma unroll
    for (int k = 0; k < 4; k++) {
        int base = k * 16;
        if (base >= deg) break;
        int cl = min(16, deg - base);
        #pragma unroll
        for (int half = 0; half < 2; half++) {
            int j0 = half * 8;
            if (j0 >= cl) break;
            float pj[8]; int sj[8];
            #pragma unroll
            for (int jj = 0; jj < 8; jj++) {
                pj[jj] = __shfl(pv[k], hb + j0 + jj);
                sj[jj] = __shfl(sv[k], hb + j0 + jj);
            }
            uint2 rv[8];
            #pragma unroll
            for (int jj = 0; jj < 8; jj++) {
                if (j0 + jj < cl) rv[jj] = *(const uint2*)(hsrc + (size_t)sj[jj] * 256 + l * 4);
            }
            #pragma unroll
            for (int jj = 0; jj < 8; jj++) {
                if (j0 + jj < cl) {
                    float2 a0 = __half22float2(*(__half2*)&rv[jj].x);
                    float2 b0 = __half22float2(*(__half2*)&rv[jj].y);
                    acc.x = fmaf(pj[jj], a0.x, acc.x); acc.y = fmaf(pj[jj], a0.y, acc.y);
                    acc.z = fmaf(pj[jj], b0.x, acc.z); acc.w = fmaf(pj[jj], b0.y, acc.w);
                }
            }
        }
    }

    float inv = 1.f / den;
    float rx = fmaxf(fmaf(acc.x, inv, bv.x), 0.f);
    float ry = fmaxf(fmaf(acc.y, inv, bv.y), 0.f);
    float rz = fmaxf(fmaf(acc.z, inv, bv.z), 0.f);
    float rw = fmaxf(fmaf(acc.w, inv, bv.w), 0.f);
    __half2* op = (__half2*)(outh + (size_t)node * 256 + l * 4);
    op[0] = __floats2half2_rn(rx, ry);
    op[1] = __floats2half2_rn(rz, rw);
}

// ---------------- GAT aggregation layer 2 (C=16, fp16 gather, MLP=4) --------

__global__ __launch_bounds__(256) void gat_agg16_f16_k(
    const __half* __restrict__ hsrc,  // [N, 64] fp16
    const float* __restrict__ as,
    const float* __restrict__ ad,
    const int* __restrict__ cnt,
    const unsigned short* __restrict__ slots,
    const float* __restrict__ bias,   // [64]
    float* __restrict__ out, int N) {
    int node = blockIdx.x * 4 + (threadIdx.x >> 6);
    if (node >= N) return;
    int l = threadIdx.x & 63;
    int ha = l >> 4;
    int je = l & 15;
    int q = l & 15;
    int hh = q >> 2;
    int eg = l >> 4;
    int deg = min(cnt[(size_t)node * CS], CAP);
    const unsigned short* sp = slots + (size_t)node * CAP;
    float adh = ad[(size_t)node * HEADS + ha];
    float m = -INFINITY, den = 0.f;
    float4 acc = make_float4(0.f, 0.f, 0.f, 0.f);
    for (int base = 0; base < deg; base += 16) {
        int cl = min(16, deg - base);
        int s = 0;
        float e = -INFINITY;
        if (je < cl) {
            s = sp[base + je];
            float a = as[(size_t)s * HEADS + ha] + adh;
            e = (a > 0.f) ? a : 0.2f * a;
        }
        float cmax = e;
        #pragma unroll
        for (int o = 8; o >= 1; o >>= 1) cmax = fmaxf(cmax, __shfl_xor(cmax, o));
        float m_new = fmaxf(m, cmax);
        float p = (je < cl) ? __expf(e - m_new) : 0.f;
        float sum = p;
        #pragma unroll
        for (int o = 8; o >= 1; o >>= 1) sum += __shfl_xor(sum, o);
        float sc = __expf(m - m_new);
        den = den * sc + sum;
        m = m_new;
        float sch = __shfl(sc, hh << 4);
        acc.x *= sch; acc.y *= sch; acc.z *= sch; acc.w *= sch;

        int jbase = eg * 4;
        float pj[4]; int sj[4]; bool vj[4];
        #pragma unroll
        for (int jj = 0; jj < 4; jj++) {
            int j = jbase + jj;
            int jc = min(j, cl - 1);
            pj[jj] = __shfl(p, (hh << 4) + jc);
            sj[jj] = __shfl(s, (hh << 4) + jc);
            vj[jj] = (j < cl);
        }
        uint2 rv[4];
        #pragma unroll
        for (int jj = 0; jj < 4; jj++) {
            if (vj[jj]) rv[jj] = *(const uint2*)(hsrc + (size_t)sj[jj] * 64 + q * 4);
        }
        #pragma unroll
        for (int jj = 0; jj < 4; jj++) {
            if (vj[jj]) {
                float2 f0 = __half22float2(*(__half2*)&rv[jj].x);
                float2 f1 = __half22float2(*(__half2*)&rv[jj].y);
                acc.x = fmaf(pj[jj], f0.x, acc.x); acc.y = fmaf(pj[jj], f0.y, acc.y);
                acc.z = fmaf(pj[jj], f1.x, acc.z); acc.w = fmaf(pj[jj], f1.y, acc.w);
            }
        }
    }
    acc.x += __shfl_xor(acc.x, 16); acc.y += __shfl_xor(acc.y, 16);
    acc.z += __shfl_xor(acc.z, 16); acc.w += __shfl_xor(acc.w, 16);
    acc.x += __shfl_xor(acc.x, 32); acc.y += __shfl_xor(acc.y, 32);
    acc.z += __shfl_xor(acc.z, 32); acc.w += __shfl_xor(acc.w, 32);
    float denh = __shfl(den, hh << 4);
    if (eg == 0) {
        float inv = 1.f / denh;
        float4 bv = *(const float4*)(bias + q * 4);
        float4 r;
        r.x = fmaxf(fmaf(acc.x, inv, bv.x), 0.f);
        r.y = fmaxf(fmaf(acc.y, inv, bv.y), 0.f);
        r.z = fmaxf(fmaf(acc.z, inv, bv.z), 0.f);
        r.w = fmaxf(fmaf(acc.w, inv, bv.w), 0.f);
        *(float4*)(out + (size_t)node * 64 + q * 4) = r;
    }
}

// ---------------- pooling + FC ----------------

__global__ __launch_bounds__(256) void bounds_zero_k(const int* __restrict__ batch, int N,
                                                     int* __restrict__ bstart,
                                                     float* __restrict__ sums) {
    int t = threadIdx.x;
    if (t <= 64) {
        int lo = 0, hi = N;
        while (lo < hi) {
            int mid = (lo + hi) >> 1;
            if (batch[mid] < t) lo = mid + 1; else hi = mid;
        }
        bstart[t] = lo;
    }
    for (int i = t; i < 64 * 64; i += 256) sums[i] = 0.f;
}

__global__ __launch_bounds__(256) void pool_sum_k(const float* __restrict__ g2,
                                                  const int* __restrict__ batch,
                                                  float* __restrict__ sums, int N) {
    int c = threadIdx.x & 63;
    int r = threadIdx.x >> 6;
    int base = blockIdx.x * 256;
    int lim = min(base + 256, N);
    float acc = 0.f;
    int cur = -1;
    for (int n = base + r; n < lim; n += 4) {
        int g = batch[n];
        if (g != cur) {
            if (cur >= 0) atomicAdd(&sums[cur * 64 + c], acc);
            acc = 0.f;
            cur = g;
        }
        acc += g2[(size_t)n * 64 + c];
    }
    if (cur >= 0) atomicAdd(&sums[cur * 64 + c], acc);
}

__global__ void fc_k(const float* __restrict__ sums, const int* __restrict__ bstart,
                     const float* __restrict__ w, const float* __restrict__ b,
                     float* __restrict__ out) {
    int g = blockIdx.x, o = threadIdx.x;  // 32 threads
    float cnt_ = (float)max(bstart[g + 1] - bstart[g], 1);
    float inv = 1.f / cnt_;
    float acc = b[o];
    for (int k = 0; k < 64; k++) acc = fmaf(sums[g * 64 + k] * inv, w[k * 32 + o], acc);
    out[g * 32 + o] = acc;
}

// ---------------- launch ----------------

static inline size_t align_up(size_t x, size_t a) { return (x + a - 1) & ~(a - 1); }

extern "C" void kernel_launch(void* const* d_in, const int* in_sizes, int n_in,
                              void* d_out, int out_size, void* d_ws, size_t ws_size,
                              hipStream_t stream) {
    const float* x      = (const float*)d_in[0];
    const int*   ei     = (const int*)d_in[1];
    const int*   batch  = (const int*)d_in[2];
    const float* W1     = (const float*)d_in[3];
    const float* a_src1 = (const float*)d_in[4];
    const float* a_dst1 = (const float*)d_in[5];
    const float* b1     = (const float*)d_in[6];
    const float* W2     = (const float*)d_in[7];
    const float* a_src2 = (const float*)d_in[8];
    const float* a_dst2 = (const float*)d_in[9];
    const float* b2     = (const float*)d_in[10];
    const float* fc_w   = (const float*)d_in[11];
    const float* fc_b   = (const float*)d_in[12];
    float* out = (float*)d_out;

    const int N = in_sizes[2];
    const int E = in_sizes[1] / 2;
    const int F_in = in_sizes[0] / N;   // 128
    const int D1 = HEADS * 64;          // 256
    const int D2 = HEADS * 16;          // 64

    const int* src = ei;
    const int* dst = ei + E;

    char* w = (char*)d_ws;
    size_t off = 0;
    auto alloc = [&](size_t bytes) {
        size_t p = off;
        off = align_up(off + bytes, 256);
        return (void*)(w + p);
    };
    int* cnt    = (int*)alloc((size_t)N * CS * 4);   // padded: 1 counter per 64B line
    unsigned short* slots = (unsigned short*)alloc((size_t)N * CAP * 2);
    int* bstart = (int*)alloc(65 * 4);
    float* pooled = (float*)alloc(64 * 64 * 4);
    float* as1  = (float*)alloc((size_t)N * HEADS * 4);
    float* ad1  = (float*)alloc((size_t)N * HEADS * 4);
    float* as2  = (float*)alloc((size_t)N * HEADS * 4);
    float* ad2  = (float*)alloc((size_t)N * HEADS * 4);
    __half* h1h = (__half*)alloc((size_t)N * D1 * 2);
    __half* g1h = (__half*)alloc((size_t)N * D1 * 2);
    __half* h2h = (__half*)alloc((size_t)N * D2 * 2);
    float* g2   = (float*)alloc((size_t)N * D2 * 4);
    _Float16* w1t = (_Float16*)alloc((size_t)F_in * D1 * 2);  // [256][128]
    _Float16* w2t = (_Float16*)alloc((size_t)D1 * D2 * 2);    // [64][256]

    // --- merged prep: cnt/slot init + W1T + W2T ---
    const int NB = (N + 255) / 256;
    prep_k<<<NB + 128 + 64, 256, 0, stream>>>(cnt, slots, N, NB, W1, w1t, W2, w2t);

    // --- fused: edge scatter (8-wide phased) ∥ layer-1 GEMM ---
    const int SB = (E + 2047) / 2048;        // 8 edges per scatter thread
    const int GB = (N + 63) / 64;
    fused_scatter_gemm1_k<<<SB + GB, 256, 0, stream>>>(
        src, dst, cnt, slots, E, SB,
        x, w1t, h1h, a_src1, a_dst1, as1, ad1, N);

    // --- layer 1 aggregation ---
    gat_agg64_f16_k<<<(N + 3) / 4, 256, 0, stream>>>(h1h, as1, ad1, cnt, slots, b1, g1h, N);

    // --- layer 2 ---
    mfma_gemm2_k<<<(N + 63) / 64, 256, 0, stream>>>((const _Float16*)g1h, w2t, h2h,
                                                    a_src2, a_dst2, as2, ad2, N);
    gat_agg16_f16_k<<<(N + 3) / 4, 256, 0, stream>>>(h2h, as2, ad2, cnt, slots, b2, g2, N);

    // --- pool + fc ---
    bounds_zero_k<<<1, 256, 0, stream>>>(batch, N, bstart, pooled);
    pool_sum_k<<<(N + 255) / 256, 256, 0, stream>>>(g2, batch, pooled, N);
    fc_k<<<64, 32, 0, stream>>>(pooled, bstart, fc_w, fc_b, out);
}

// Round 10
// 308.206 us; speedup vs baseline: 1.8004x; 1.0172x over previous
//
#include <hip/hip_runtime.h>
#include <hip/hip_bf16.h>
#include <hip/hip_fp16.h>
#include <math.h>

#define HEADS 4
#define CAP 64    // max in-degree incl. self-loop (Poisson(17) tail; clamped)
#define CS 16     // cnt stride in ints: one counter per 64B line

typedef _Float16 half8_t __attribute__((ext_vector_type(8)));
typedef float float4_t __attribute__((ext_vector_type(4)));

// -------- merged prep: cnt/slots init + W1^T fp16 + W2^T fp16 ---------------

__global__ __launch_bounds__(256) void prep_k(int* cnt, unsigned short* slots, int N, int NB,
                                              const float* __restrict__ W1, _Float16* __restrict__ W1T,
                                              const float* __restrict__ W2, _Float16* __restrict__ W2T) {
    int bx = blockIdx.x;
    if (bx < NB) {
        int i = bx * 256 + threadIdx.x;
        if (i < N) {
            cnt[(size_t)i * CS] = 1;
            slots[(size_t)i * CAP] = (unsigned short)i;
        }
    } else if (bx < NB + 128) {
        int k = bx - NB;           // 0..127
        int n = threadIdx.x;       // 0..255
        W1T[n * 128 + k] = (_Float16)W1[k * 256 + n];
    } else {
        int n = bx - NB - 128;     // 0..63
        int k = threadIdx.x;       // 0..255
        W2T[n * 256 + k] = (_Float16)W2[k * 64 + n];
    }
}

// ---------------- fused: edge scatter (8-wide phased MLP) ∥ MFMA GEMM1 ------

__global__ __launch_bounds__(256) void fused_scatter_gemm1_k(
    const int* __restrict__ src, const int* __restrict__ dst,
    int* __restrict__ cnt, unsigned short* __restrict__ slots, int E, int SB,
    const float* __restrict__ A,       // [M][128] fp32 (x)
    const _Float16* __restrict__ BT,   // [256][128] (W1^T)
    __half* __restrict__ hout,         // [M][256] fp16
    const float* __restrict__ avs,     // [4][64]
    const float* __restrict__ avd,
    float* __restrict__ os,            // [M][4]
    float* __restrict__ od, int M) {
    __shared__ _Float16 lds[4 * 16 * 72];   // 9 KB; per-wave 16x64 chunk (stride 72)

    if ((int)blockIdx.x < SB) {
        // ---- scatter branch: 8 edges per thread, phased for MLP ----
        int T = SB * 256;
        int t0 = blockIdx.x * 256 + threadIdx.x;
        int d[8], s[8];
        #pragma unroll
        for (int k = 0; k < 8; k++) {
            int i = t0 + k * T;
            if (i < E) { d[k] = dst[i]; s[k] = src[i]; }
            else d[k] = -1;
        }
        int p[8];
        #pragma unroll
        for (int k = 0; k < 8; k++) {
            if (d[k] >= 0) p[k] = atomicAdd(&cnt[(size_t)d[k] * CS], 1);
        }
        #pragma unroll
        for (int k = 0; k < 8; k++) {
            if (d[k] >= 0 && p[k] < CAP)
                slots[(size_t)d[k] * CAP + p[k]] = (unsigned short)s[k];
        }
        return;
    }

    // ---- GEMM1 branch ----
    int bx = blockIdx.x - SB;
    int wave = threadIdx.x >> 6;
    int lane = threadIdx.x & 63;
    int q = lane >> 4;
    int c16 = lane & 15;
    int row0 = bx * 64 + wave * 16;

    half8_t a[4];
    int ar = row0 + c16;
    bool avalid = (ar < M);
    const float* ap = A + (size_t)ar * 128;
    #pragma unroll
    for (int ks = 0; ks < 4; ks++) {
        if (avalid) {
            float4 f0 = *(const float4*)(ap + ks * 32 + q * 8);
            float4 f1 = *(const float4*)(ap + ks * 32 + q * 8 + 4);
            half8_t h;
            h[0] = (_Float16)f0.x; h[1] = (_Float16)f0.y;
            h[2] = (_Float16)f0.z; h[3] = (_Float16)f0.w;
            h[4] = (_Float16)f1.x; h[5] = (_Float16)f1.y;
            h[6] = (_Float16)f1.z; h[7] = (_Float16)f1.w;
            a[ks] = h;
        } else {
            a[ks] = (half8_t)(_Float16)0.0f;
        }
    }

    float4_t acc[16];
    #pragma unroll
    for (int ct = 0; ct < 16; ct++) acc[ct] = (float4_t)0.f;

    #pragma unroll
    for (int ks = 0; ks < 4; ks++) {
        #pragma unroll
        for (int ct = 0; ct < 16; ct++) {
            half8_t b = *(const half8_t*)(BT + (size_t)(ct * 16 + c16) * 128 + ks * 32 + q * 8);
            acc[ct] = __builtin_amdgcn_mfma_f32_16x16x32_f16(a[ks], b, acc[ct], 0, 0, 0);
        }
    }

    // alpha dot partials (head h = ct>>2, chan-in-head = (ct&3)*16 + c16)
    float psh[4][4] = {}, pdh[4][4] = {};
    #pragma unroll
    for (int ct = 0; ct < 16; ct++) {
        int h = ct >> 2;
        int cih = (ct & 3) * 16 + c16;
        float as_v = avs[h * 64 + cih];
        float ad_v = avd[h * 64 + cih];
        #pragma unroll
        for (int r = 0; r < 4; r++) {
            psh[h][r] = fmaf(acc[ct][r], as_v, psh[h][r]);
            pdh[h][r] = fmaf(acc[ct][r], ad_v, pdh[h][r]);
        }
    }
    #pragma unroll
    for (int h = 0; h < 4; h++) {
        #pragma unroll
        for (int r = 0; r < 4; r++) {
            #pragma unroll
            for (int o = 8; o >= 1; o >>= 1) {
                psh[h][r] += __shfl_down(psh[h][r], o, 16);
                pdh[h][r] += __shfl_down(pdh[h][r], o, 16);
            }
        }
    }
    if (c16 == 0) {
        #pragma unroll
        for (int r = 0; r < 4; r++) {
            int gr = row0 + q * 4 + r;
            if (gr < M) {
                #pragma unroll
                for (int h = 0; h < 4; h++) {
                    os[(size_t)gr * HEADS + h] = psh[h][r];
                    od[(size_t)gr * HEADS + h] = pdh[h][r];
                }
            }
        }
    }

    // fp16 store via per-wave chunked LDS staging (stride 72 halfs = 144 B)
    _Float16* wl = lds + wave * (16 * 72);
    #pragma unroll
    for (int chunk = 0; chunk < 4; chunk++) {
        #pragma unroll
        for (int c4 = 0; c4 < 4; c4++) {
            int ct = chunk * 4 + c4;
            #pragma unroll
            for (int r = 0; r < 4; r++) {
                wl[(q * 4 + r) * 72 + c4 * 16 + c16] = (_Float16)acc[ct][r];
            }
        }
        __syncthreads();
        #pragma unroll
        for (int pass = 0; pass < 2; pass++) {
            int idx8 = pass * 64 + lane;   // 128 half8 units (16 rows x 8)
            int row = idx8 >> 3;
            int col8 = idx8 & 7;
            int gr = row0 + row;
            if (gr < M) {
                *(half8_t*)(hout + (size_t)gr * 256 + chunk * 64 + col8 * 8) =
                    *(const half8_t*)(wl + row * 72 + col8 * 8);
            }
        }
        __syncthreads();
    }
}

// ------- fused: GAT agg layer 1 (C=64) + MFMA GEMM2 (g1 never leaves LDS) ---
// Block = 16 nodes, 4 waves. Gather phase: wave w runs the proven agg64 body
// on nodes nb+w*4+i (i=0..3), writing post-ReLU g1 fp16 rows to LDS (stride
// 264 halfs, 16B aligned). One barrier. MFMA phase: wave w computes output
// cols ct=w (16 cols) of h2 = g1 @ W2 for all 16 rows; head ct's alpha dot
// is wave-local. Eliminates the 25.6MB g1h write + 25.6MB read + 1 dispatch.

__global__ __launch_bounds__(256) void fused_agg64_gemm2_k(
    const __half* __restrict__ hsrc,   // [N, 256] fp16 (h1)
    const float* __restrict__ as,      // as1 [N,4]
    const float* __restrict__ ad,      // ad1 [N,4]
    const int* __restrict__ cnt,       // [N*CS] strided degree
    const unsigned short* __restrict__ slots,  // [N*CAP]
    const float* __restrict__ bias1,   // b1 [256]
    const _Float16* __restrict__ BT,   // w2t [64][256]
    const float* __restrict__ avs2,    // a_src2 [4][16]
    const float* __restrict__ avd2,    // a_dst2 [4][16]
    __half* __restrict__ h2out,        // [N, 64] fp16
    float* __restrict__ os2,           // as2 [N,4]
    float* __restrict__ od2,           // ad2 [N,4]
    int N) {
    __shared__ __align__(16) _Float16 g1t[16 * 264];   // 16 rows x 256 (stride 264)

    int wave = threadIdx.x >> 6;
    int lane = threadIdx.x & 63;
    int nb = blockIdx.x * 16;

    // ---- gather phase (agg64 body, 4 nodes per wave) ----
    int h = lane >> 4;
    int je = lane & 15;
    int hb = h << 4;
    float4 bv = *(const float4*)(bias1 + lane * 4);

    for (int i = 0; i < 4; i++) {
        int row = wave * 4 + i;
        int node = nb + row;
        _Float16* grow = g1t + row * 264;
        __half2* gp = (__half2*)(grow + lane * 4);
        if (node >= N) {
            __half2 z = __floats2half2_rn(0.f, 0.f);
            gp[0] = z; gp[1] = z;
            continue;
        }
        int deg = min(cnt[(size_t)node * CS], CAP);
        const unsigned short* sp = slots + (size_t)node * CAP;
        float adh = ad[(size_t)node * HEADS + h];

        // phase 1: all e values
        int sv[4];
        float ev[4];
        #pragma unroll
        for (int k = 0; k < 4; k++) {
            int j = k * 16 + je;
            sv[k] = (j < deg) ? (int)sp[j] : 0;
        }
        #pragma unroll
        for (int k = 0; k < 4; k++) {
            int j = k * 16 + je;
            if (j < deg) {
                float a = as[(size_t)sv[k] * HEADS + h] + adh;
                ev[k] = (a > 0.f) ? a : 0.2f * a;
            } else {
                ev[k] = -INFINITY;
            }
        }
        float m = fmaxf(fmaxf(ev[0], ev[1]), fmaxf(ev[2], ev[3]));
        #pragma unroll
        for (int o = 8; o >= 1; o >>= 1) m = fmaxf(m, __shfl_xor(m, o));
        float pv[4];
        float den = 0.f;
        #pragma unroll
        for (int k = 0; k < 4; k++) {
            pv[k] = (k * 16 + je < deg) ? __expf(ev[k] - m) : 0.f;
            den += pv[k];
        }
        #pragma unroll
        for (int o = 8; o >= 1; o >>= 1) den += __shfl_xor(den, o);

        // phase 2: accumulate, 8 row-loads in flight
        float4 acc = make_float4(0.f, 0.f, 0.f, 0.f);
        #pragma unroll
        for (int k = 0; k < 4; k++) {
            int base = k * 16;
            if (base >= deg) break;
            int cl = min(16, deg - base);
            #pragma unroll
            for (int hf = 0; hf < 2; hf++) {
                int j0 = hf * 8;
                if (j0 >= cl) break;
                float pj[8]; int sj[8];
                #pragma unroll
                for (int jj = 0; jj < 8; jj++) {
                    pj[jj] = __shfl(pv[k], hb + j0 + jj);
                    sj[jj] = __shfl(sv[k], hb + j0 + jj);
                }
                uint2 rv[8];
                #pragma unroll
                for (int jj = 0; jj < 8; jj++) {
                    if (j0 + jj < cl) rv[jj] = *(const uint2*)(hsrc + (size_t)sj[jj] * 256 + lane * 4);
                }
                #pragma unroll
                for (int jj = 0; jj < 8; jj++) {
                    if (j0 + jj < cl) {
                        float2 a0 = __half22float2(*(__half2*)&rv[jj].x);
                        float2 b0 = __half22float2(*(__half2*)&rv[jj].y);
                        acc.x = fmaf(pj[jj], a0.x, acc.x); acc.y = fmaf(pj[jj], a0.y, acc.y);
                        acc.z = fmaf(pj[jj], b0.x, acc.z); acc.w = fmaf(pj[jj], b0.y, acc.w);
                    }
                }
            }
        }

        float inv = 1.f / den;
        float rx = fmaxf(fmaf(acc.x, inv, bv.x), 0.f);
        float ry = fmaxf(fmaf(acc.y, inv, bv.y), 0.f);
        float rz = fmaxf(fmaf(acc.z, inv, bv.z), 0.f);
        float rw = fmaxf(fmaf(acc.w, inv, bv.w), 0.f);
        gp[0] = __floats2half2_rn(rx, ry);
        gp[1] = __floats2half2_rn(rz, rw);
    }
    __syncthreads();

    // ---- MFMA phase: wave ct computes cols ct*16..ct*16+15 for 16 rows ----
    int q = lane >> 4;
    int c16 = lane & 15;
    int ct = wave;
    float4_t acc2 = (float4_t)0.f;
    #pragma unroll
    for (int ks = 0; ks < 8; ks++) {
        half8_t av = *(const half8_t*)(g1t + c16 * 264 + ks * 32 + q * 8);
        half8_t bv8 = *(const half8_t*)(BT + (size_t)(ct * 16 + c16) * 256 + ks * 32 + q * 8);
        acc2 = __builtin_amdgcn_mfma_f32_16x16x32_f16(av, bv8, acc2, 0, 0, 0);
    }

    float as_v = avs2[ct * 16 + c16];
    float ad_v = avd2[ct * 16 + c16];
    float ps[4], pd[4];
    #pragma unroll
    for (int r = 0; r < 4; r++) {
        ps[r] = acc2[r] * as_v;
        pd[r] = acc2[r] * ad_v;
        #pragma unroll
        for (int o = 8; o >= 1; o >>= 1) {
            ps[r] += __shfl_down(ps[r], o, 16);
            pd[r] += __shfl_down(pd[r], o, 16);
        }
    }
    #pragma unroll
    for (int r = 0; r < 4; r++) {
        int gr = nb + q * 4 + r;
        if (gr < N) {
            h2out[(size_t)gr * 64 + ct * 16 + c16] = __float2half(acc2[r]);
            if (c16 == 0) {
                os2[(size_t)gr * HEADS + ct] = ps[r];
                od2[(size_t)gr * HEADS + ct] = pd[r];
            }
        }
    }
}

// ---------------- GAT aggregation layer 2 (C=16, fp16 gather, MLP=4) --------

__global__ __launch_bounds__(256) void gat_agg16_f16_k(
    const __half* __restrict__ hsrc,  // [N, 64] fp16
    const float* __restrict__ as,
    const float* __restrict__ ad,
    const int* __restrict__ cnt,
    const unsigned short* __restrict__ slots,
    const float* __restrict__ bias,   // [64]
    float* __restrict__ out, int N) {
    int node = blockIdx.x * 4 + (threadIdx.x >> 6);
    if (node >= N) return;
    int l = threadIdx.x & 63;
    int ha = l >> 4;
    int je = l & 15;
    int q = l & 15;
    int hh = q >> 2;
    int eg = l >> 4;
    int deg = min(cnt[(size_t)node * CS], CAP);
    const unsigned short* sp = slots + (size_t)node * CAP;
    float adh = ad[(size_t)node * HEADS + ha];
    float m = -INFINITY, den = 0.f;
    float4 acc = make_float4(0.f, 0.f, 0.f, 0.f);
    for (int base = 0; base < deg; base += 16) {
        int cl = min(16, deg - base);
        int s = 0;
        float e = -INFINITY;
        if (je < cl) {
            s = sp[base + je];
            float a = as[(size_t)s * HEADS + ha] + adh;
            e = (a > 0.f) ? a : 0.2f * a;
        }
        float cmax = e;
        #pragma unroll
        for (int o = 8; o >= 1; o >>= 1) cmax = fmaxf(cmax, __shfl_xor(cmax, o));
        float m_new = fmaxf(m, cmax);
        float p = (je < cl) ? __expf(e - m_new) : 0.f;
        float sum = p;
        #pragma unroll
        for (int o = 8; o >= 1; o >>= 1) sum += __shfl_xor(sum, o);
        float sc = __expf(m - m_new);
        den = den * sc + sum;
        m = m_new;
        float sch = __shfl(sc, hh << 4);
        acc.x *= sch; acc.y *= sch; acc.z *= sch; acc.w *= sch;

        int jbase = eg * 4;
        float pj[4]; int sj[4]; bool vj[4];
        #pragma unroll
        for (int jj = 0; jj < 4; jj++) {
            int j = jbase + jj;
            int jc = min(j, cl - 1);
            pj[jj] = __shfl(p, (hh << 4) + jc);
            sj[jj] = __shfl(s, (hh << 4) + jc);
            vj[jj] = (j < cl);
        }
        uint2 rv[4];
        #pragma unroll
        for (int jj = 0; jj < 4; jj++) {
            if (vj[jj]) rv[jj] = *(const uint2*)(hsrc + (size_t)sj[jj] * 64 + q * 4);
        }
        #pragma unroll
        for (int jj = 0; jj < 4; jj++) {
            if (vj[jj]) {
                float2 f0 = __half22float2(*(__half2*)&rv[jj].x);
                float2 f1 = __half22float2(*(__half2*)&rv[jj].y);
                acc.x = fmaf(pj[jj], f0.x, acc.x); acc.y = fmaf(pj[jj], f0.y, acc.y);
                acc.z = fmaf(pj[jj], f1.x, acc.z); acc.w = fmaf(pj[jj], f1.y, acc.w);
            }
        }
    }
    acc.x += __shfl_xor(acc.x, 16); acc.y += __shfl_xor(acc.y, 16);
    acc.z += __shfl_xor(acc.z, 16); acc.w += __shfl_xor(acc.w, 16);
    acc.x += __shfl_xor(acc.x, 32); acc.y += __shfl_xor(acc.y, 32);
    acc.z += __shfl_xor(acc.z, 32); acc.w += __shfl_xor(acc.w, 32);
    float denh = __shfl(den, hh << 4);
    if (eg == 0) {
        float inv = 1.f / denh;
        float4 bv = *(const float4*)(bias + q * 4);
        float4 r;
        r.x = fmaxf(fmaf(acc.x, inv, bv.x), 0.f);
        r.y = fmaxf(fmaf(acc.y, inv, bv.y), 0.f);
        r.z = fmaxf(fmaf(acc.z, inv, bv.z), 0.f);
        r.w = fmaxf(fmaf(acc.w, inv, bv.w), 0.f);
        *(float4*)(out + (size_t)node * 64 + q * 4) = r;
    }
}

// ---------------- pooling + FC ----------------

__global__ __launch_bounds__(256) void bounds_zero_k(const int* __restrict__ batch, int N,
                                                     int* __restrict__ bstart,
                                                     float* __restrict__ sums) {
    int t = threadIdx.x;
    if (t <= 64) {
        int lo = 0, hi = N;
        while (lo < hi) {
            int mid = (lo + hi) >> 1;
            if (batch[mid] < t) lo = mid + 1; else hi = mid;
        }
        bstart[t] = lo;
    }
    for (int i = t; i < 64 * 64; i += 256) sums[i] = 0.f;
}

__global__ __launch_bounds__(256) void pool_sum_k(const float* __restrict__ g2,
                                                  const int* __restrict__ batch,
                                                  float* __restrict__ sums, int N) {
    int c = threadIdx.x & 63;
    int r = threadIdx.x >> 6;
    int base = blockIdx.x * 256;
    int lim = min(base + 256, N);
    float acc = 0.f;
    int cur = -1;
    for (int n = base + r; n < lim; n += 4) {
        int g = batch[n];
        if (g != cur) {
            if (cur >= 0) atomicAdd(&sums[cur * 64 + c], acc);
            acc = 0.f;
            cur = g;
        }
        acc += g2[(size_t)n * 64 + c];
    }
    if (cur >= 0) atomicAdd(&sums[cur * 64 + c], acc);
}

__global__ void fc_k(const float* __restrict__ sums, const int* __restrict__ bstart,
                     const float* __restrict__ w, const float* __restrict__ b,
                     float* __restrict__ out) {
    int g = blockIdx.x, o = threadIdx.x;  // 32 threads
    float cnt_ = (float)max(bstart[g + 1] - bstart[g], 1);
    float inv = 1.f / cnt_;
    float acc = b[o];
    for (int k = 0; k < 64; k++) acc = fmaf(sums[g * 64 + k] * inv, w[k * 32 + o], acc);
    out[g * 32 + o] = acc;
}

// ---------------- launch ----------------

static inline size_t align_up(size_t x, size_t a) { return (x + a - 1) & ~(a - 1); }

extern "C" void kernel_launch(void* const* d_in, const int* in_sizes, int n_in,
                              void* d_out, int out_size, void* d_ws, size_t ws_size,
                              hipStream_t stream) {
    const float* x      = (const float*)d_in[0];
    const int*   ei     = (const int*)d_in[1];
    const int*   batch  = (const int*)d_in[2];
    const float* W1     = (const float*)d_in[3];
    const float* a_src1 = (const float*)d_in[4];
    const float* a_dst1 = (const float*)d_in[5];
    const float* b1     = (const float*)d_in[6];
    const float* W2     = (const float*)d_in[7];
    const float* a_src2 = (const float*)d_in[8];
    const float* a_dst2 = (const float*)d_in[9];
    const float* b2     = (const float*)d_in[10];
    const float* fc_w   = (const float*)d_in[11];
    const float* fc_b   = (const float*)d_in[12];
    float* out = (float*)d_out;

    const int N = in_sizes[2];
    const int E = in_sizes[1] / 2;
    const int F_in = in_sizes[0] / N;   // 128
    const int D1 = HEADS * 64;          // 256
    const int D2 = HEADS * 16;          // 64

    const int* src = ei;
    const int* dst = ei + E;

    char* w = (char*)d_ws;
    size_t off = 0;
    auto alloc = [&](size_t bytes) {
        size_t p = off;
        off = align_up(off + bytes, 256);
        return (void*)(w + p);
    };
    int* cnt    = (int*)alloc((size_t)N * CS * 4);   // padded: 1 counter per 64B line
    unsigned short* slots = (unsigned short*)alloc((size_t)N * CAP * 2);
    int* bstart = (int*)alloc(65 * 4);
    float* pooled = (float*)alloc(64 * 64 * 4);
    float* as1  = (float*)alloc((size_t)N * HEADS * 4);
    float* ad1  = (float*)alloc((size_t)N * HEADS * 4);
    float* as2  = (float*)alloc((size_t)N * HEADS * 4);
    float* ad2  = (float*)alloc((size_t)N * HEADS * 4);
    __half* h1h = (__half*)alloc((size_t)N * D1 * 2);
    __half* h2h = (__half*)alloc((size_t)N * D2 * 2);
    float* g2   = (float*)alloc((size_t)N * D2 * 4);
    _Float16* w1t = (_Float16*)alloc((size_t)F_in * D1 * 2);  // [256][128]
    _Float16* w2t = (_Float16*)alloc((size_t)D1 * D2 * 2);    // [64][256]

    // --- merged prep: cnt/slot init + W1T + W2T ---
    const int NB = (N + 255) / 256;
    prep_k<<<NB + 128 + 64, 256, 0, stream>>>(cnt, slots, N, NB, W1, w1t, W2, w2t);

    // --- fused: edge scatter (8-wide phased) ∥ layer-1 GEMM ---
    const int SB = (E + 2047) / 2048;        // 8 edges per scatter thread
    const int GB = (N + 63) / 64;
    fused_scatter_gemm1_k<<<SB + GB, 256, 0, stream>>>(
        src, dst, cnt, slots, E, SB,
        x, w1t, h1h, a_src1, a_dst1, as1, ad1, N);

    // --- fused: layer-1 aggregation + layer-2 GEMM (g1 stays in LDS) ---
    fused_agg64_gemm2_k<<<(N + 15) / 16, 256, 0, stream>>>(
        h1h, as1, ad1, cnt, slots, b1,
        w2t, a_src2, a_dst2, h2h, as2, ad2, N);

    // --- layer 2 aggregation ---
    gat_agg16_f16_k<<<(N + 3) / 4, 256, 0, stream>>>(h2h, as2, ad2, cnt, slots, b2, g2, N);

    // --- pool + fc ---
    bounds_zero_k<<<1, 256, 0, stream>>>(batch, N, bstart, pooled);
    pool_sum_k<<<(N + 255) / 256, 256, 0, stream>>>(g2, batch, pooled, N);
    fc_k<<<64, 32, 0, stream>>>(pooled, bstart, fc_w, fc_b, out);
}